// Round 3
// baseline (461.378 us; speedup 1.0000x reference)
//
#include <hip/hip_runtime.h>
#include <hip/hip_bf16.h>
#include <math.h>

// Problem constants
#define BB 2
#define SS 2048
#define EE 1024
#define HH 16
#define HD 64
#define FFF 4096
#define MROWS (BB * SS)        // 4096
#define EPS_F 1.1920929e-7f
#define NQKV 1152              // 1024 q + 64 k + 64 v

typedef __hip_bfloat16 bf16;
typedef __attribute__((ext_vector_type(8))) short short8;
typedef __attribute__((ext_vector_type(4))) short short4v;
typedef __attribute__((ext_vector_type(4))) float floatx4;

typedef const __attribute__((address_space(1))) void* gas_t;
typedef __attribute__((address_space(3))) void* las_t;

// scheduling primitives for the 8-phase FFN kernel
#define BAR __builtin_amdgcn_s_barrier()
#define WLG do { asm volatile("s_waitcnt lgkmcnt(0)" ::: "memory"); \
                 __builtin_amdgcn_sched_barrier(0); } while (0)
#define VMC(N) asm volatile("s_waitcnt vmcnt(" #N ")" ::: "memory")

// ---------------------------------------------------------------------------
// RMSNorm: fp32 in, bf16 out
// ---------------------------------------------------------------------------
__global__ __launch_bounds__(256) void rmsnorm_kernel(const float* __restrict__ x,
                                                      const float* __restrict__ g,
                                                      bf16* __restrict__ out,
                                                      int cols) {
    int row = blockIdx.x;
    const float* xr = x + (size_t)row * cols;
    float ss = 0.0f;
    for (int c = threadIdx.x; c < cols; c += 256) {
        float v = xr[c];
        ss += v * v;
    }
    for (int off = 32; off > 0; off >>= 1) ss += __shfl_xor(ss, off, 64);
    __shared__ float red[4];
    int wave = threadIdx.x >> 6;
    if ((threadIdx.x & 63) == 0) red[wave] = ss;
    __syncthreads();
    float tot = red[0] + red[1] + red[2] + red[3];
    float rs = rsqrtf(tot / (float)cols + EPS_F);
    bf16* orow = out + (size_t)row * cols;
    for (int c = threadIdx.x; c < cols; c += 256) {
        orow[c] = __float2bfloat16(xr[c] * rs * g[c]);
    }
}

// ---------------------------------------------------------------------------
// Cast + transpose: W (K x N, fp32) -> Wt (N x K, bf16). 32x32 LDS tiles.
// ---------------------------------------------------------------------------
__global__ __launch_bounds__(256) void transpose_cast_kernel(const float* __restrict__ W,
                                                             bf16* __restrict__ Wt,
                                                             int K, int N) {
    __shared__ float t[32][33];
    int n0 = blockIdx.x * 32, k0 = blockIdx.y * 32;
    int tx = threadIdx.x & 31, ty = threadIdx.x >> 5;   // ty 0..7
#pragma unroll
    for (int i = 0; i < 4; ++i) {
        int kk = ty + i * 8;
        t[kk][tx] = W[(size_t)(k0 + kk) * N + n0 + tx];
    }
    __syncthreads();
#pragma unroll
    for (int i = 0; i < 4; ++i) {
        int nn = ty + i * 8;
        Wt[(size_t)(n0 + nn) * K + k0 + tx] = __float2bfloat16(t[tx][nn]);
    }
}

// pack [bq | bk | bv] -> bqkv (1152 floats)
__global__ __launch_bounds__(256) void pack_bqkv_kernel(const float* __restrict__ bq,
                                                        const float* __restrict__ bk,
                                                        const float* __restrict__ bv,
                                                        float* __restrict__ bqkv) {
    int t = blockIdx.x * 256 + threadIdx.x;
    if (t >= NQKV) return;
    float v;
    if (t < 1024)      v = bq[t];
    else if (t < 1088) v = bk[t - 1024];
    else               v = bv[t - 1088];
    bqkv[t] = v;
}

// ---------------------------------------------------------------------------
// Fused QKV GEMM: [q|k|v] = h1 @ [wq|wk|wv]^T + bqkv.
// 128x128 tiles, BK=64, global_load_lds staging. N = 1152.
// cols < 1024 -> qbf (bf16, stride 1024); cols >= 1024 -> kv (fp32, stride 128)
// ---------------------------------------------------------------------------
#define GK 64

__global__ __launch_bounds__(256) void gemm_qkv_kernel(
        const bf16* __restrict__ A, const bf16* __restrict__ Bt,
        const float* __restrict__ bias,
        bf16* __restrict__ qout, float* __restrict__ kvout, int K) {
    __shared__ short As[128 * GK];
    __shared__ short Bs[128 * GK];
    int tid = threadIdx.x;
    int wave = tid >> 6, lane = tid & 63;
    int wm = (wave >> 1) * 64, wn = (wave & 1) * 64;
    int row0 = blockIdx.y * 128, col0 = blockIdx.x * 128;
    int lr = lane & 15, lq = lane >> 4;

    int srow = wave * 32 + (lane >> 3);
    int scol = (lane & 7) * 8;
    const bf16* Abase = A + (size_t)(row0 + srow) * K + scol;
    const bf16* Bbase = Bt + (size_t)(col0 + srow) * K + scol;

    floatx4 acc[4][4];
#pragma unroll
    for (int mi = 0; mi < 4; ++mi)
#pragma unroll
        for (int ni = 0; ni < 4; ++ni)
            acc[mi][ni] = (floatx4){0.f, 0.f, 0.f, 0.f};

    for (int k0 = 0; k0 < K; k0 += GK) {
        __syncthreads();
#pragma unroll
        for (int c = 0; c < 4; ++c) {
            __builtin_amdgcn_global_load_lds(
                (gas_t)(Abase + (size_t)(c * 8) * K + k0),
                (las_t)&As[(wave * 32 + c * 8) * GK], 16, 0, 0);
            __builtin_amdgcn_global_load_lds(
                (gas_t)(Bbase + (size_t)(c * 8) * K + k0),
                (las_t)&Bs[(wave * 32 + c * 8) * GK], 16, 0, 0);
        }
        __syncthreads();
#pragma unroll
        for (int ks = 0; ks < GK; ks += 32) {
            short8 af[4], bfr[4];
#pragma unroll
            for (int mi = 0; mi < 4; ++mi)
                af[mi] = *(const short8*)&As[(wm + mi * 16 + lr) * GK + ks + lq * 8];
#pragma unroll
            for (int ni = 0; ni < 4; ++ni)
                bfr[ni] = *(const short8*)&Bs[(wn + ni * 16 + lr) * GK + ks + lq * 8];
#pragma unroll
            for (int mi = 0; mi < 4; ++mi)
#pragma unroll
                for (int ni = 0; ni < 4; ++ni)
                    acc[mi][ni] = __builtin_amdgcn_mfma_f32_16x16x32_bf16(
                        af[mi], bfr[ni], acc[mi][ni], 0, 0, 0);
        }
    }

#pragma unroll
    for (int mi = 0; mi < 4; ++mi) {
#pragma unroll
        for (int ni = 0; ni < 4; ++ni) {
            int gc = col0 + wn + ni * 16 + lr;
            float bv = bias[gc];
#pragma unroll
            for (int r = 0; r < 4; ++r) {
                int gr = row0 + wm + mi * 16 + lq * 4 + r;
                float c = acc[mi][ni][r] + bv;
                if (gc < 1024) qout[(size_t)gr * 1024 + gc] = __float2bfloat16(c);
                else           kvout[(size_t)gr * 128 + (gc - 1024)] = c;
            }
        }
    }
}

// ---------------------------------------------------------------------------
// GEMM 128x128 tiles (wo, wd): C = A@Bt^T + bias + aux. fp32 out.
// Same proven structure/MFMA order as gemm_qkv (bit-identical per element);
// replaces the 128x64 gemm_n64 (half the staging bytes per MFMA).
// ---------------------------------------------------------------------------
__global__ __launch_bounds__(256) void gemm_n128_kernel(
        const bf16* __restrict__ A, const bf16* __restrict__ Bt,
        const float* __restrict__ bias, const float* __restrict__ aux,
        float* __restrict__ C, int N, int K) {
    __shared__ short As[128 * GK];
    __shared__ short Bs[128 * GK];
    int tid = threadIdx.x;
    int wave = tid >> 6, lane = tid & 63;
    int wm = (wave >> 1) * 64, wn = (wave & 1) * 64;
    int row0 = blockIdx.y * 128, col0 = blockIdx.x * 128;
    int lr = lane & 15, lq = lane >> 4;

    int srow = wave * 32 + (lane >> 3);
    int scol = (lane & 7) * 8;
    const bf16* Abase = A + (size_t)(row0 + srow) * K + scol;
    const bf16* Bbase = Bt + (size_t)(col0 + srow) * K + scol;

    floatx4 acc[4][4];
#pragma unroll
    for (int mi = 0; mi < 4; ++mi)
#pragma unroll
        for (int ni = 0; ni < 4; ++ni)
            acc[mi][ni] = (floatx4){0.f, 0.f, 0.f, 0.f};

    for (int k0 = 0; k0 < K; k0 += GK) {
        __syncthreads();
#pragma unroll
        for (int c = 0; c < 4; ++c) {
            __builtin_amdgcn_global_load_lds(
                (gas_t)(Abase + (size_t)(c * 8) * K + k0),
                (las_t)&As[(wave * 32 + c * 8) * GK], 16, 0, 0);
            __builtin_amdgcn_global_load_lds(
                (gas_t)(Bbase + (size_t)(c * 8) * K + k0),
                (las_t)&Bs[(wave * 32 + c * 8) * GK], 16, 0, 0);
        }
        __syncthreads();
#pragma unroll
        for (int ks = 0; ks < GK; ks += 32) {
            short8 af[4], bfr[4];
#pragma unroll
            for (int mi = 0; mi < 4; ++mi)
                af[mi] = *(const short8*)&As[(wm + mi * 16 + lr) * GK + ks + lq * 8];
#pragma unroll
            for (int ni = 0; ni < 4; ++ni)
                bfr[ni] = *(const short8*)&Bs[(wn + ni * 16 + lr) * GK + ks + lq * 8];
#pragma unroll
            for (int mi = 0; mi < 4; ++mi)
#pragma unroll
                for (int ni = 0; ni < 4; ++ni)
                    acc[mi][ni] = __builtin_amdgcn_mfma_f32_16x16x32_bf16(
                        af[mi], bfr[ni], acc[mi][ni], 0, 0, 0);
        }
    }

#pragma unroll
    for (int mi = 0; mi < 4; ++mi) {
#pragma unroll
        for (int ni = 0; ni < 4; ++ni) {
            int gc = col0 + wn + ni * 16 + lr;
            float bv = bias[gc];
#pragma unroll
            for (int r = 0; r < 4; ++r) {
                int gr = row0 + wm + mi * 16 + lq * 4 + r;
                size_t idx = (size_t)gr * N + gc;
                C[idx] = acc[mi][ni][r] + bv + aux[idx];
            }
        }
    }
}

// ---------------------------------------------------------------------------
// Fused FFN GEMM, 8-phase schedule (T3+T4+T5):
//   gg = gelu(h2@wgT^T + bg) * (h2@wuT^T + bu)
// BM=256 x BN=128 output tile; staged B = G(128 rows) + U(128 rows) -> same
// geometry as the verified 256^2 8-phase template: 8 waves (512 thr),
// 64 MFMA per K-tile per wave in 4 phases of 16, one 16KB half-tile staged
// per phase (2 x global_load_lds/thread), counted vmcnt (never 0 mid-loop).
//
// Half-tile order (K-tile k = [A-k0 | B-k0 | A-k1 | B-k1], buffers by k&1):
//   prologue: t0A0 t0B0 t0A1 t0B1 t1A0 t1B0 ; vmcnt(8)
//   phase1(k): reads kh0/mh0, stages tile k+1 A-k1
//   phase2(k): reads kh0/mh1, stages tile k+1 B-k1 ; vmcnt(8) [k=NT-1: 0]
//   phase3(k): reads kh1/mh0, stages tile k+2 A-k0   (region dead since ph2)
//   phase4(k): reads kh1/mh1, stages tile k+2 B-k0 ; vmcnt(8) [k=NT-2: 4]
// Safety: every staging write targets a region whose last ds_read completed
// (lgkmcnt(0)) before a barrier preceding the staging issue. Accumulation
// order per output element (k asc, K-half asc) identical to the old kernel.
// ---------------------------------------------------------------------------
#define FFN_RD(KH, MH) \
    short8 af[4], gf[2], uf[2]; \
    { const short* Ap = &Ab[buf][KH][0]; const short* Bp = &Bb[buf][KH][0]; \
      af[0] = *(const short8*)&Ap[(wr * 128 + ((MH) * 4 + 0) * 16 + lr) * 32 + quad * 8]; \
      af[1] = *(const short8*)&Ap[(wr * 128 + ((MH) * 4 + 1) * 16 + lr) * 32 + quad * 8]; \
      af[2] = *(const short8*)&Ap[(wr * 128 + ((MH) * 4 + 2) * 16 + lr) * 32 + quad * 8]; \
      af[3] = *(const short8*)&Ap[(wr * 128 + ((MH) * 4 + 3) * 16 + lr) * 32 + quad * 8]; \
      gf[0] = *(const short8*)&Bp[(wc * 32 + lr) * 32 + quad * 8]; \
      gf[1] = *(const short8*)&Bp[(wc * 32 + 16 + lr) * 32 + quad * 8]; \
      uf[0] = *(const short8*)&Bp[4096 + (wc * 32 + lr) * 32 + quad * 8]; \
      uf[1] = *(const short8*)&Bp[4096 + (wc * 32 + 16 + lr) * 32 + quad * 8]; }

#define FFN_MM(MH) \
    __builtin_amdgcn_s_setprio(1); \
    { _Pragma("unroll") for (int mi = 0; mi < 4; ++mi) { \
        ag[(MH) * 4 + mi][0] = __builtin_amdgcn_mfma_f32_16x16x32_bf16(af[mi], gf[0], ag[(MH) * 4 + mi][0], 0, 0, 0); \
        ag[(MH) * 4 + mi][1] = __builtin_amdgcn_mfma_f32_16x16x32_bf16(af[mi], gf[1], ag[(MH) * 4 + mi][1], 0, 0, 0); \
        au[(MH) * 4 + mi][0] = __builtin_amdgcn_mfma_f32_16x16x32_bf16(af[mi], uf[0], au[(MH) * 4 + mi][0], 0, 0, 0); \
        au[(MH) * 4 + mi][1] = __builtin_amdgcn_mfma_f32_16x16x32_bf16(af[mi], uf[1], au[(MH) * 4 + mi][1], 0, 0, 0); } } \
    __builtin_amdgcn_s_setprio(0);

__global__ __launch_bounds__(512, 2) void gemm_ffn_kernel(
        const bf16* __restrict__ A, const bf16* __restrict__ Bg,
        const bf16* __restrict__ Bu, const float* __restrict__ biasg,
        const float* __restrict__ biasu, bf16* __restrict__ C, int K) {
    __shared__ short Ab[2][2][8192];   // [buf][khalf][256 rows x 32 cols]
    __shared__ short Bb[2][2][8192];   // [buf][khalf][G 128 rows | U 128 rows]

    const int tid = threadIdx.x;
    const int w = tid >> 6, lane = tid & 63;
    const int wr = w >> 2, wc = w & 3;           // 2M x 4N waves
    const int lr = lane & 15, quad = lane >> 4;
    const int row0 = blockIdx.y * 256, col0 = blockIdx.x * 128;
    const int NT = K >> 6;                       // 16 K-tiles

    const int sr = tid >> 2;                     // staging row 0..127
    const int sc = (tid & 3) * 8;                // staging col offset

    auto stageA = [&](short* dst, int kcol) {
        __builtin_amdgcn_global_load_lds(
            (gas_t)(A + (size_t)(row0 + sr) * K + kcol + sc),
            (las_t)(dst + tid * 8), 16, 0, 0);
        __builtin_amdgcn_global_load_lds(
            (gas_t)(A + (size_t)(row0 + 128 + sr) * K + kcol + sc),
            (las_t)(dst + 4096 + tid * 8), 16, 0, 0);
    };
    auto stageB = [&](short* dst, int kcol) {
        __builtin_amdgcn_global_load_lds(
            (gas_t)(Bg + (size_t)(col0 + sr) * K + kcol + sc),
            (las_t)(dst + tid * 8), 16, 0, 0);
        __builtin_amdgcn_global_load_lds(
            (gas_t)(Bu + (size_t)(col0 + sr) * K + kcol + sc),
            (las_t)(dst + 4096 + tid * 8), 16, 0, 0);
    };

    floatx4 ag[8][2], au[8][2];
#pragma unroll
    for (int mi = 0; mi < 8; ++mi)
#pragma unroll
        for (int ni = 0; ni < 2; ++ni) {
            ag[mi][ni] = (floatx4){0.f, 0.f, 0.f, 0.f};
            au[mi][ni] = (floatx4){0.f, 0.f, 0.f, 0.f};
        }

    // prologue: 6 half-tiles; drain to 8 outstanding loads (t0A0,t0B0 landed)
    stageA(&Ab[0][0][0], 0);
    stageB(&Bb[0][0][0], 0);
    stageA(&Ab[0][1][0], 32);
    stageB(&Bb[0][1][0], 32);
    stageA(&Ab[1][0][0], 64);
    stageB(&Bb[1][0][0], 64);
    VMC(8);
    BAR;

    for (int k = 0; k < NT; ++k) {
        const int buf = k & 1;
        {   // phase 1: kh0, mh0 | stage tile k+1 A-k1
            FFN_RD(0, 0)
            if (k + 1 < NT) stageA(&Ab[buf ^ 1][1][0], (k + 1) * 64 + 32);
            BAR; WLG;
            FFN_MM(0)
            BAR;
        }
        {   // phase 2: kh0, mh1 | stage tile k+1 B-k1 | vmcnt: tile k A1/B1... next needs k's kh1
            FFN_RD(0, 1)
            if (k + 1 < NT) stageB(&Bb[buf ^ 1][1][0], (k + 1) * 64 + 32);
            BAR; WLG;
            FFN_MM(1)
            if (k < NT - 1) { VMC(8); } else { VMC(0); }
            BAR;
        }
        {   // phase 3: kh1, mh0 | stage tile k+2 A-k0 (region dead since ph2)
            FFN_RD(1, 0)
            if (k + 2 < NT) stageA(&Ab[buf][0][0], (k + 2) * 64);
            BAR; WLG;
            FFN_MM(0)
            BAR;
        }
        {   // phase 4: kh1, mh1 | stage tile k+2 B-k0 | vmcnt: tile k+1 A0/B0 landed
            FFN_RD(1, 1)
            if (k + 2 < NT) stageB(&Bb[buf][0][0], (k + 2) * 64);
            BAR; WLG;
            FFN_MM(1)
            if (k < NT - 2) { VMC(8); } else if (k == NT - 2) { VMC(4); }
            BAR;
        }
    }

#pragma unroll
    for (int mi = 0; mi < 8; ++mi) {
#pragma unroll
        for (int ni = 0; ni < 2; ++ni) {
            int gc = col0 + wc * 32 + ni * 16 + lr;
            float bg_ = biasg[gc], bu_ = biasu[gc];
#pragma unroll
            for (int r = 0; r < 4; ++r) {
                int gr = row0 + wr * 128 + mi * 16 + quad * 4 + r;
                float g = ag[mi][ni][r] + bg_;
                float u = au[mi][ni][r] + bu_;
                float v = 0.5f * g * (1.0f + erff(g * 0.70710678118654752f)) * u;
                C[(size_t)gr * FFF + gc] = __float2bfloat16(v);
            }
        }
    }
}

// ---------------------------------------------------------------------------
// RoPE cos/sin table: (SS x 32) each. Identical math (powf/cosf/sinf) to the
// per-element version, computed once per (s,i) instead of once per (s,i,h).
// ---------------------------------------------------------------------------
__global__ __launch_bounds__(256) void rope_table_kernel(float* __restrict__ ct,
                                                         float* __restrict__ st) {
    int idx = blockIdx.x * 256 + threadIdx.x;   // SS*32 = 65536 total
    int i = idx & 31, s = idx >> 5;
    float inv = powf(10000.0f, -(float)i / 32.0f);
    float ang = (float)s * inv;
    ct[idx] = cosf(ang);
    st[idx] = sinf(ang);
}

// ---------------------------------------------------------------------------
// RoPE on bf16 q, in place, 1/sqrt(HD) folded. pos = row % SS. Table-driven.
// ---------------------------------------------------------------------------
__global__ __launch_bounds__(256) void rope_q_kernel(bf16* __restrict__ t,
                                                     const float* __restrict__ ct,
                                                     const float* __restrict__ st,
                                                     int total) {
    int idx = blockIdx.x * 256 + threadIdx.x;
    if (idx >= total) return;
    int i = idx & 31;
    int h = (idx >> 5) % HH;
    int row = idx / (32 * HH);
    int s = row & (SS - 1);
    float c = ct[s * 32 + i];
    float sn = st[s * 32 + i];
    size_t base = (size_t)row * (HH * HD) + h * 64 + i;
    float t1 = (float)t[base];
    float t2 = (float)t[base + 32];
    t[base]      = __float2bfloat16((t1 * c - t2 * sn) * 0.125f);
    t[base + 32] = __float2bfloat16((t1 * sn + t2 * c) * 0.125f);
}

// ---------------------------------------------------------------------------
// prep_kv: kv fp32 (MROWS,128) -> kbf bf16 (MROWS,64) roped,
//          vtb bf16 (BB,64,SS) = V transposed per batch. Table-driven RoPE.
// ---------------------------------------------------------------------------
__global__ __launch_bounds__(256) void prep_kv_kernel(const float* __restrict__ kv,
                                                      const float* __restrict__ ct,
                                                      const float* __restrict__ st,
                                                      bf16* __restrict__ kbf,
                                                      bf16* __restrict__ vtb) {
    __shared__ float vt[64][65];
    int s0 = blockIdx.x * 64;
    int b  = blockIdx.y;
    int tid = threadIdx.x;

    for (int i = tid; i < 2048; i += 256) {
        int sl = i >> 5, ii = i & 31;
        int s = s0 + sl;
        size_t base = ((size_t)(b * SS + s)) * 128;
        float k1 = kv[base + ii], k2 = kv[base + ii + 32];
        float c = ct[s * 32 + ii];
        float sn = st[s * 32 + ii];
        size_t ob = ((size_t)(b * SS + s)) * 64;
        kbf[ob + ii]      = __float2bfloat16(k1 * c - k2 * sn);
        kbf[ob + ii + 32] = __float2bfloat16(k1 * sn + k2 * c);
    }

    for (int i = tid; i < 4096; i += 256) {
        int s = i >> 6, d = i & 63;
        vt[d][s] = kv[((size_t)(b * SS + s0 + s)) * 128 + 64 + d];
    }
    __syncthreads();
    for (int i = tid; i < 4096; i += 256) {
        int d = i >> 6, sl = i & 63;
        vtb[((size_t)(b * 64 + d)) * SS + s0 + sl] = __float2bfloat16(vt[d][sl]);
    }
}

// ---------------------------------------------------------------------------
// MFMA flash attention v6: fixed-shift softmax + k-split-2 (unchanged math)
// with LDS-staged, double-buffered K/V tiles. XOR-swizzled (both-sides).
// ---------------------------------------------------------------------------
#define PST 68
#define SM_SHIFT 6.0f

__global__ __launch_bounds__(256, 3) void attn_mfma_kernel(
        const bf16* __restrict__ q, const bf16* __restrict__ kb,
        const bf16* __restrict__ vt,
        float* __restrict__ O0p, float* __restrict__ O1p,
        float* __restrict__ l0p, float* __restrict__ l1p) {
    __shared__ short Kb_s[2][64 * 64];
    __shared__ short Vb_s[2][64 * 64];
    __shared__ short Ps[4][16 * PST];

    int h = blockIdx.y, b = blockIdx.z;
    int px = blockIdx.x >> 1, half = blockIdx.x & 1;
    int tid = threadIdx.x, w = tid >> 6, lane = tid & 63;
    int lr = lane & 15, quad = lane >> 4;
    int rsw = lane & 7;                 // read-side swizzle: row&7 == lr&7

    float* __restrict__ Op = half ? O1p : O0p;
    float* __restrict__ lp = half ? l1p : l0p;

    const bf16* kbB = kb + (size_t)b * SS * 64;
    const bf16* vtB = vt + (size_t)b * 64 * SS;

    int st_sub = lane >> 3;
    int st_col = ((lane & 7) ^ st_sub) << 3;      // element offset within row

    auto stage_tile = [&](int nxt, int j0s) {
#pragma unroll
        for (int i = 0; i < 2; ++i) {
            int rr = i * 32 + w * 8 + st_sub;
            __builtin_amdgcn_global_load_lds(
                (gas_t)(kbB + (size_t)(j0s + rr) * 64 + st_col),
                (las_t)&Kb_s[nxt][(i * 256 + w * 64) * 8], 16, 0, 0);
            __builtin_amdgcn_global_load_lds(
                (gas_t)(vtB + (size_t)rr * SS + j0s + st_col),
                (las_t)&Vb_s[nxt][(i * 256 + w * 64) * 8], 16, 0, 0);
        }
    };

    for (int pass = 0; pass < 2; ++pass) {
        int qt = (pass == 0) ? px : (SS / 64 - 1 - px);
        int q0 = qt * 64;

        const bf16* qrow = q + ((size_t)(b * SS + q0 + w * 16 + lr)) * (HH * HD) + h * HD;
        short8 qf0 = *(const short8*)(qrow + quad * 8);
        short8 qf1 = *(const short8*)(qrow + 32 + quad * 8);

        int n  = qt + 1;            // total k-tiles for this q-tile
        int n0 = (n + 1) >> 1;      // half 0 takes [0,n0), half 1 takes [n0,n)
        int tlo = half ? n0 : 0;
        int thi = half ? n  : n0;

        floatx4 O[4];
#pragma unroll
        for (int ni = 0; ni < 4; ++ni) O[ni] = (floatx4){0.f, 0.f, 0.f, 0.f};
        float lrow[4] = {0.f, 0.f, 0.f, 0.f};

        int cur = 0;
        if (tlo < thi) stage_tile(0, tlo * 64);
        __syncthreads();

        for (int t = tlo; t < thi; ++t) {
            // stage next tile into the other buffer (overlaps this compute)
            if (t + 1 < thi) stage_tile(cur ^ 1, (t + 1) * 64);

            int j0 = t * 64;

            // S = Q @ K^T   (K fragments from swizzled LDS)
            floatx4 S[4];
#pragma unroll
            for (int ni = 0; ni < 4; ++ni) S[ni] = (floatx4){0.f, 0.f, 0.f, 0.f};
#pragma unroll
            for (int ni = 0; ni < 4; ++ni) {
                const short* Kc = &Kb_s[cur][(ni * 16 + lr) * 64];
                short8 b0 = *(const short8*)&Kc[(quad ^ rsw) * 8];
                short8 b1 = *(const short8*)&Kc[((quad ^ rsw) ^ 4) * 8];
                S[ni] = __builtin_amdgcn_mfma_f32_16x16x32_bf16(qf0, b0, S[ni], 0, 0, 0);
                S[ni] = __builtin_amdgcn_mfma_f32_16x16x32_bf16(qf1, b1, S[ni], 0, 0, 0);
            }

            // V fragments (swizzled LDS), issued early to overlap exp + pack
            short8 vf[8];
#pragma unroll
            for (int ni = 0; ni < 4; ++ni) {
                const short* Vc = &Vb_s[cur][(ni * 16 + lr) * 64];
                vf[2 * ni]     = *(const short8*)&Vc[(quad ^ rsw) * 8];
                vf[2 * ni + 1] = *(const short8*)&Vc[((quad ^ rsw) ^ 4) * 8];
            }

            // causal mask on diagonal tile
            if (t == qt) {
                int rowg = q0 + w * 16 + quad * 4;
#pragma unroll
                for (int ni = 0; ni < 4; ++ni) {
                    int colg = j0 + ni * 16 + lr;
#pragma unroll
                    for (int r = 0; r < 4; ++r)
                        if (colg > rowg + r) S[ni][r] = -3.0e38f;
                }
            }

            // fixed-shift exp; accumulate per-lane row sums (no cross-lane ops)
#pragma unroll
            for (int ni = 0; ni < 4; ++ni)
#pragma unroll
                for (int r = 0; r < 4; ++r)
                    S[ni][r] = __expf(S[ni][r] - SM_SHIFT);
#pragma unroll
            for (int r = 0; r < 4; ++r)
                lrow[r] += S[0][r] + S[1][r] + S[2][r] + S[3][r];

            // pack P (bf16) to wave-private LDS in C-layout
#pragma unroll
            for (int ni = 0; ni < 4; ++ni)
#pragma unroll
                for (int r = 0; r < 4; ++r) {
                    bf16 pb = __float2bfloat16(S[ni][r]);
                    Ps[w][(quad * 4 + r) * PST + ni * 16 + lr] = *(short*)&pb;
                }
            short4v a0 = *(const short4v*)&Ps[w][lr * PST + quad * 8];
            short4v a1 = *(const short4v*)&Ps[w][lr * PST + quad * 8 + 4];
            short4v a2 = *(const short4v*)&Ps[w][lr * PST + 32 + quad * 8];
            short4v a3 = *(const short4v*)&Ps[w][lr * PST + 32 + quad * 8 + 4];
            short8 p0 = __builtin_shufflevector(a0, a1, 0, 1, 2, 3, 4, 5, 6, 7);
            short8 p1 = __builtin_shufflevector(a2, a3, 0, 1, 2, 3, 4, 5, 6, 7);

            // O += P @ V
#pragma unroll
            for (int ni = 0; ni < 4; ++ni) {
                O[ni] = __builtin_amdgcn_mfma_f32_16x16x32_bf16(p0, vf[2 * ni], O[ni], 0, 0, 0);
                O[ni] = __builtin_amdgcn_mfma_f32_16x16x32_bf16(p1, vf[2 * ni + 1], O[ni], 0, 0, 0);
            }

            // drains next-tile staging + ensures all waves done with cur
            __syncthreads();
            cur ^= 1;
        }

        // deferred row-sum reduction over the quad's 16 lanes (once per pass)
#pragma unroll
        for (int r = 0; r < 4; ++r) {
            float l = lrow[r];
            for (int off = 1; off < 16; off <<= 1) l += __shfl_xor(l, off, 64);
            lrow[r] = l;
        }

        // write unnormalized partials (zeros when this half's range is empty)
#pragma unroll
        for (int ni = 0; ni < 4; ++ni) {
            int gc = h * 64 + ni * 16 + lr;
#pragma unroll
            for (int r = 0; r < 4; ++r) {
                int gr = b * SS + q0 + w * 16 + quad * 4 + r;
                Op[(size_t)gr * (HH * HD) + gc] = O[ni][r];
            }
        }
        if (lr == 0) {
#pragma unroll
            for (int r = 0; r < 4; ++r) {
                int gr = b * SS + q0 + w * 16 + quad * 4 + r;
                lp[(size_t)gr * HH + h] = lrow[r];
            }
        }
    }
}

// ---------------------------------------------------------------------------
// Combine the two key-range halves: ao = (O0+O1)/(l0+l1), bf16 out.
// ---------------------------------------------------------------------------
__global__ __launch_bounds__(256) void attn_combine_kernel(
        const float* __restrict__ O0p, const float* __restrict__ O1p,
        const float* __restrict__ l0p, const float* __restrict__ l1p,
        bf16* __restrict__ o) {
    int idx = blockIdx.x * 256 + threadIdx.x;   // < MROWS*1024/4
    int d4  = idx & 15;
    int hh  = (idx >> 4) & 15;
    int row = idx >> 8;
    float l = l0p[row * HH + hh] + l1p[row * HH + hh];
    float inv = 1.0f / l;
    size_t base = (size_t)row * (HH * HD) + hh * 64 + d4 * 4;
    float4 a = *(const float4*)(O0p + base);
    float4 c = *(const float4*)(O1p + base);
    short4v o4;
    {
        bf16 v0 = __float2bfloat16((a.x + c.x) * inv);
        bf16 v1 = __float2bfloat16((a.y + c.y) * inv);
        bf16 v2 = __float2bfloat16((a.z + c.z) * inv);
        bf16 v3 = __float2bfloat16((a.w + c.w) * inv);
        o4[0] = *(short*)&v0; o4[1] = *(short*)&v1;
        o4[2] = *(short*)&v2; o4[3] = *(short*)&v3;
    }
    *(short4v*)(o + base) = o4;
}

// ---------------------------------------------------------------------------
// Launch. Workspace (byte offsets, ~87 MB):
//   qbf @0 (8 MB, dead after attn; wgT reuses @0) | wuT @8M
//   x2 @16M (fp32 16 MB, written step 6; Opart0 borrows @16M during attn)
//   h1b/h2b @32M (8 MB) | kv @40M (fp32 2 MB)
//   ao @42M (8 MB, dead after wo; wdT reuses)
//   gg @50M (32 MB; pre-FFN its body hosts kbf/vtb @50M, Opart1 @51M,
//            lparts @67M, rope tables @68M — all dead before gg is written)
//   wqkvT @82M (2.25 MB) | bqkv @84.5M | woT @85M (2 MB)
// ---------------------------------------------------------------------------
#define MB (1024ull * 1024ull)

extern "C" void kernel_launch(void* const* d_in, const int* in_sizes, int n_in,
                              void* d_out, int out_size, void* d_ws, size_t ws_size,
                              hipStream_t stream) {
    const float* x  = (const float*)d_in[0];
    const float* wq = (const float*)d_in[1];
    const float* bq = (const float*)d_in[2];
    const float* wk = (const float*)d_in[3];
    const float* bk = (const float*)d_in[4];
    const float* wv = (const float*)d_in[5];
    const float* bv = (const float*)d_in[6];
    const float* wo = (const float*)d_in[7];
    const float* bo = (const float*)d_in[8];
    const float* wg = (const float*)d_in[9];
    const float* bg = (const float*)d_in[10];
    const float* wu = (const float*)d_in[11];
    const float* bu = (const float*)d_in[12];
    const float* wd = (const float*)d_in[13];
    const float* bd = (const float*)d_in[14];
    const float* g1 = (const float*)d_in[15];
    const float* g2 = (const float*)d_in[16];
    float* out = (float*)d_out;

    char* ws = (char*)d_ws;
    bf16*  qbf   = (bf16*)(ws);
    bf16*  wuT   = (bf16*)(ws + 8 * MB);
    float* x2    = (float*)(ws + 16 * MB);
    bf16*  h1b   = (bf16*)(ws + 32 * MB);
    float* kv    = (float*)(ws + 40 * MB);
    bf16*  ao    = (bf16*)(ws + 42 * MB);
    bf16*  gg    = (bf16*)(ws + 50 * MB);
    bf16*  kbf   = (bf16*)(ws + 50 * MB);              // over gg head (dead by FFN)
    bf16*  vtb   = (bf16*)(ws + 50 * MB + 512 * 1024);
    float* Opart0 = (float*)(ws + 16 * MB);            // over x2 (written step 6)
    float* Opart1 = (float*)(ws + 51 * MB);            // inside gg body (16 MB)
    float* lpart0 = (float*)(ws + 67 * MB);            // 256 KB
    float* lpart1 = (float*)(ws + 67 * MB + 256 * 1024);
    float* ctab   = (float*)(ws + 68 * MB);            // 256 KB
    float* stab   = (float*)(ws + 68 * MB + 256 * 1024);
    bf16*  wqkvT = (bf16*)(ws + 82 * MB);              // 1152 x 1024 bf16
    float* bqkv  = (float*)(ws + 84 * MB + 512 * 1024);
    bf16*  woT   = (bf16*)(ws + 85 * MB);
    bf16*  wgT   = (bf16*)(ws);                        // over qbf (dead after attn)
    bf16*  wdT   = (bf16*)(ws + 42 * MB);              // over ao (dead after wo GEMM)
    bf16*  h2b   = h1b;

    // 1. h1 = rmsnorm(x, g1)
    rmsnorm_kernel<<<MROWS, 256, 0, stream>>>(x, g1, h1b, EE);

    // 2. weight transposes for attention block (wq|wk|wv packed rows)
    transpose_cast_kernel<<<dim3(EE / 32, EE / 32), 256, 0, stream>>>(wq, wqkvT, EE, EE);
    transpose_cast_kernel<<<dim3(HD / 32, EE / 32), 256, 0, stream>>>(wk, wqkvT + (size_t)1024 * EE, EE, HD);
    transpose_cast_kernel<<<dim3(HD / 32, EE / 32), 256, 0, stream>>>(wv, wqkvT + (size_t)1088 * EE, EE, HD);
    pack_bqkv_kernel<<<(NQKV + 255) / 256, 256, 0, stream>>>(bq, bk, bv, bqkv);
    transpose_cast_kernel<<<dim3(EE / 32, EE / 32), 256, 0, stream>>>(wo, woT, EE, EE);

    // 3. fused QKV projection
    gemm_qkv_kernel<<<dim3(NQKV / 128, MROWS / 128), 256, 0, stream>>>(
        h1b, wqkvT, bqkv, qbf, kv, EE);

    // 3.5 RoPE cos/sin table (once per launch; identical math to before)
    rope_table_kernel<<<(SS * 32) / 256, 256, 0, stream>>>(ctab, stab);

    // 4. RoPE on q (in place, 0.125 folded); kv -> kbf (roped) + vtb
    {
        int total_q = MROWS * HH * 32;
        rope_q_kernel<<<(total_q + 255) / 256, 256, 0, stream>>>(qbf, ctab, stab, total_q);
    }
    prep_kv_kernel<<<dim3(SS / 64, BB), 256, 0, stream>>>(kv, ctab, stab, kbf, vtb);

    // 5. attention partials (k-split x2) + combine -> ao [bf16]
    attn_mfma_kernel<<<dim3(2 * SS / 128, HH, BB), 256, 0, stream>>>(
        qbf, kbf, vtb, Opart0, Opart1, lpart0, lpart1);
    attn_combine_kernel<<<(MROWS * HH * HD / 4) / 256, 256, 0, stream>>>(
        Opart0, Opart1, lpart0, lpart1, ao);

    // 6. x2 = ao @ wo + bo + x  [fp32]
    gemm_n128_kernel<<<dim3(EE / 128, MROWS / 128), 256, 0, stream>>>(
        ao, woT, bo, x, x2, EE, EE);

    // 7. h2 = rmsnorm(x2, g2)
    rmsnorm_kernel<<<MROWS, 256, 0, stream>>>(x2, g2, h2b, EE);

    // 8. FFN weight transposes (reuse dead qbf slot + wuT region)
    transpose_cast_kernel<<<dim3(FFF / 32, EE / 32), 256, 0, stream>>>(wg, wgT, EE, FFF);
    transpose_cast_kernel<<<dim3(FFF / 32, EE / 32), 256, 0, stream>>>(wu, wuT, EE, FFF);

    // 9. gg = gelu(h2@wg+bg) * (h2@wu+bu)  [fused, 8-phase, bf16]
    gemm_ffn_kernel<<<dim3(FFF / 128, MROWS / 256), 512, 0, stream>>>(
        h2b, wgT, wuT, bg, bu, gg, EE);

    // 10. wd transpose, then out = gg @ wd + bd + x2  [fp32]
    transpose_cast_kernel<<<dim3(EE / 32, FFF / 32), 256, 0, stream>>>(wd, wdT, FFF, EE);
    gemm_n128_kernel<<<dim3(EE / 128, MROWS / 128), 256, 0, stream>>>(
        gg, wdT, bd, x2, out, EE, FFF);
}

// Round 4
// 429.013 us; speedup vs baseline: 1.0754x; 1.0754x over previous
//
#include <hip/hip_runtime.h>
#include <hip/hip_bf16.h>
#include <math.h>

// Problem constants
#define BB 2
#define SS 2048
#define EE 1024
#define HH 16
#define HD 64
#define FFF 4096
#define MROWS (BB * SS)        // 4096
#define EPS_F 1.1920929e-7f
#define NQKV 1152              // 1024 q + 64 k + 64 v

typedef __hip_bfloat16 bf16;
typedef __attribute__((ext_vector_type(8))) short short8;
typedef __attribute__((ext_vector_type(4))) short short4v;
typedef __attribute__((ext_vector_type(4))) float floatx4;

typedef const __attribute__((address_space(1))) void* gas_t;
typedef __attribute__((address_space(3))) void* las_t;

// scheduling primitives for the 8-phase FFN kernel
#define BAR __builtin_amdgcn_s_barrier()
#define WLG do { asm volatile("s_waitcnt lgkmcnt(0)" ::: "memory"); \
                 __builtin_amdgcn_sched_barrier(0); } while (0)
#define VMC(N) asm volatile("s_waitcnt vmcnt(" #N ")" ::: "memory")

// ---------------------------------------------------------------------------
// RMSNorm: fp32 in, bf16 out
// ---------------------------------------------------------------------------
__global__ __launch_bounds__(256) void rmsnorm_kernel(const float* __restrict__ x,
                                                      const float* __restrict__ g,
                                                      bf16* __restrict__ out,
                                                      int cols) {
    int row = blockIdx.x;
    const float* xr = x + (size_t)row * cols;
    float ss = 0.0f;
    for (int c = threadIdx.x; c < cols; c += 256) {
        float v = xr[c];
        ss += v * v;
    }
    for (int off = 32; off > 0; off >>= 1) ss += __shfl_xor(ss, off, 64);
    __shared__ float red[4];
    int wave = threadIdx.x >> 6;
    if ((threadIdx.x & 63) == 0) red[wave] = ss;
    __syncthreads();
    float tot = red[0] + red[1] + red[2] + red[3];
    float rs = rsqrtf(tot / (float)cols + EPS_F);
    bf16* orow = out + (size_t)row * cols;
    for (int c = threadIdx.x; c < cols; c += 256) {
        orow[c] = __float2bfloat16(xr[c] * rs * g[c]);
    }
}

// ---------------------------------------------------------------------------
// Cast + transpose: W (K x N, fp32) -> Wt (N x K, bf16). 32x32 LDS tiles.
// ---------------------------------------------------------------------------
__global__ __launch_bounds__(256) void transpose_cast_kernel(const float* __restrict__ W,
                                                             bf16* __restrict__ Wt,
                                                             int K, int N) {
    __shared__ float t[32][33];
    int n0 = blockIdx.x * 32, k0 = blockIdx.y * 32;
    int tx = threadIdx.x & 31, ty = threadIdx.x >> 5;   // ty 0..7
#pragma unroll
    for (int i = 0; i < 4; ++i) {
        int kk = ty + i * 8;
        t[kk][tx] = W[(size_t)(k0 + kk) * N + n0 + tx];
    }
    __syncthreads();
#pragma unroll
    for (int i = 0; i < 4; ++i) {
        int nn = ty + i * 8;
        Wt[(size_t)(n0 + nn) * K + k0 + tx] = __float2bfloat16(t[tx][nn]);
    }
}

// pack [bq | bk | bv] -> bqkv (1152 floats)
__global__ __launch_bounds__(256) void pack_bqkv_kernel(const float* __restrict__ bq,
                                                        const float* __restrict__ bk,
                                                        const float* __restrict__ bv,
                                                        float* __restrict__ bqkv) {
    int t = blockIdx.x * 256 + threadIdx.x;
    if (t >= NQKV) return;
    float v;
    if (t < 1024)      v = bq[t];
    else if (t < 1088) v = bk[t - 1024];
    else               v = bv[t - 1088];
    bqkv[t] = v;
}

// ---------------------------------------------------------------------------
// Fused QKV GEMM: [q|k|v] = h1 @ [wq|wk|wv]^T + bqkv.
// 128x128 tiles, BK=64, global_load_lds staging. N = 1152.
// cols < 1024 -> qbf (bf16, stride 1024); cols >= 1024 -> kv (fp32, stride 128)
// ---------------------------------------------------------------------------
#define GK 64

__global__ __launch_bounds__(256) void gemm_qkv_kernel(
        const bf16* __restrict__ A, const bf16* __restrict__ Bt,
        const float* __restrict__ bias,
        bf16* __restrict__ qout, float* __restrict__ kvout, int K) {
    __shared__ short As[128 * GK];
    __shared__ short Bs[128 * GK];
    int tid = threadIdx.x;
    int wave = tid >> 6, lane = tid & 63;
    int wm = (wave >> 1) * 64, wn = (wave & 1) * 64;
    int row0 = blockIdx.y * 128, col0 = blockIdx.x * 128;
    int lr = lane & 15, lq = lane >> 4;

    int srow = wave * 32 + (lane >> 3);
    int scol = (lane & 7) * 8;
    const bf16* Abase = A + (size_t)(row0 + srow) * K + scol;
    const bf16* Bbase = Bt + (size_t)(col0 + srow) * K + scol;

    floatx4 acc[4][4];
#pragma unroll
    for (int mi = 0; mi < 4; ++mi)
#pragma unroll
        for (int ni = 0; ni < 4; ++ni)
            acc[mi][ni] = (floatx4){0.f, 0.f, 0.f, 0.f};

    for (int k0 = 0; k0 < K; k0 += GK) {
        __syncthreads();
#pragma unroll
        for (int c = 0; c < 4; ++c) {
            __builtin_amdgcn_global_load_lds(
                (gas_t)(Abase + (size_t)(c * 8) * K + k0),
                (las_t)&As[(wave * 32 + c * 8) * GK], 16, 0, 0);
            __builtin_amdgcn_global_load_lds(
                (gas_t)(Bbase + (size_t)(c * 8) * K + k0),
                (las_t)&Bs[(wave * 32 + c * 8) * GK], 16, 0, 0);
        }
        __syncthreads();
#pragma unroll
        for (int ks = 0; ks < GK; ks += 32) {
            short8 af[4], bfr[4];
#pragma unroll
            for (int mi = 0; mi < 4; ++mi)
                af[mi] = *(const short8*)&As[(wm + mi * 16 + lr) * GK + ks + lq * 8];
#pragma unroll
            for (int ni = 0; ni < 4; ++ni)
                bfr[ni] = *(const short8*)&Bs[(wn + ni * 16 + lr) * GK + ks + lq * 8];
#pragma unroll
            for (int mi = 0; mi < 4; ++mi)
#pragma unroll
                for (int ni = 0; ni < 4; ++ni)
                    acc[mi][ni] = __builtin_amdgcn_mfma_f32_16x16x32_bf16(
                        af[mi], bfr[ni], acc[mi][ni], 0, 0, 0);
        }
    }

#pragma unroll
    for (int mi = 0; mi < 4; ++mi) {
#pragma unroll
        for (int ni = 0; ni < 4; ++ni) {
            int gc = col0 + wn + ni * 16 + lr;
            float bv = bias[gc];
#pragma unroll
            for (int r = 0; r < 4; ++r) {
                int gr = row0 + wm + mi * 16 + lq * 4 + r;
                float c = acc[mi][ni][r] + bv;
                if (gc < 1024) qout[(size_t)gr * 1024 + gc] = __float2bfloat16(c);
                else           kvout[(size_t)gr * 128 + (gc - 1024)] = c;
            }
        }
    }
}

// ---------------------------------------------------------------------------
// GEMM 128x64 tiles (for N=1024 outputs: wo, wd): C = A@Bt^T + bias + aux.
// 4 waves, each 32 rows x 64 cols (mi=2, ni=4). fp32 out, fp32 aux residual.
// 512 blocks = 2/CU — this parallelism is load-bearing (n128@256blocks lost).
// ---------------------------------------------------------------------------
__global__ __launch_bounds__(256) void gemm_n64_kernel(
        const bf16* __restrict__ A, const bf16* __restrict__ Bt,
        const float* __restrict__ bias, const float* __restrict__ aux,
        float* __restrict__ C, int M, int N, int K) {
    __shared__ short As[128 * GK];
    __shared__ short Bs[64 * GK];
    int tid = threadIdx.x;
    int wave = tid >> 6, lane = tid & 63;
    int wm = wave * 32;
    int row0 = blockIdx.y * 128, col0 = blockIdx.x * 64;
    int lr = lane & 15, lq = lane >> 4;

    int srow = (lane >> 3);
    int scol = (lane & 7) * 8;
    const bf16* Abase = A + (size_t)(row0 + wave * 32 + srow) * K + scol;
    const bf16* Bbase = Bt + (size_t)(col0 + wave * 16 + srow) * K + scol;

    floatx4 acc[2][4];
#pragma unroll
    for (int mi = 0; mi < 2; ++mi)
#pragma unroll
        for (int ni = 0; ni < 4; ++ni)
            acc[mi][ni] = (floatx4){0.f, 0.f, 0.f, 0.f};

    for (int k0 = 0; k0 < K; k0 += GK) {
        __syncthreads();
#pragma unroll
        for (int c = 0; c < 4; ++c)
            __builtin_amdgcn_global_load_lds(
                (gas_t)(Abase + (size_t)(c * 8) * K + k0),
                (las_t)&As[(wave * 32 + c * 8) * GK], 16, 0, 0);
#pragma unroll
        for (int c = 0; c < 2; ++c)
            __builtin_amdgcn_global_load_lds(
                (gas_t)(Bbase + (size_t)(c * 8) * K + k0),
                (las_t)&Bs[(wave * 16 + c * 8) * GK], 16, 0, 0);
        __syncthreads();
#pragma unroll
        for (int ks = 0; ks < GK; ks += 32) {
            short8 af[2], bfr[4];
#pragma unroll
            for (int mi = 0; mi < 2; ++mi)
                af[mi] = *(const short8*)&As[(wm + mi * 16 + lr) * GK + ks + lq * 8];
#pragma unroll
            for (int ni = 0; ni < 4; ++ni)
                bfr[ni] = *(const short8*)&Bs[(ni * 16 + lr) * GK + ks + lq * 8];
#pragma unroll
            for (int mi = 0; mi < 2; ++mi)
#pragma unroll
                for (int ni = 0; ni < 4; ++ni)
                    acc[mi][ni] = __builtin_amdgcn_mfma_f32_16x16x32_bf16(
                        af[mi], bfr[ni], acc[mi][ni], 0, 0, 0);
        }
    }

#pragma unroll
    for (int mi = 0; mi < 2; ++mi) {
#pragma unroll
        for (int ni = 0; ni < 4; ++ni) {
            int gc = col0 + ni * 16 + lr;
            float bv = bias[gc];
#pragma unroll
            for (int r = 0; r < 4; ++r) {
                int gr = row0 + wm + mi * 16 + lq * 4 + r;
                size_t idx = (size_t)gr * N + gc;
                C[idx] = acc[mi][ni][r] + bv + aux[idx];
            }
        }
    }
}

// ---------------------------------------------------------------------------
// Fused FFN GEMM, 8-phase schedule (T2+T3+T4+T5):
//   gg = gelu(h2@wgT^T + bg) * (h2@wuT^T + bu)
// Round-3 postmortem: 28% MfmaUtil == predicted LDS-read-bound with 4-way
// conflicts (64B rows: consecutive-8 lanes hit 2 bank-groups). Fixes:
//  (a) chunk swizzle: 16B chunk c of row r stored at c ^ ((r>>1)&3)
//      (pre-swizzled GLOBAL source + swizzled ds_read; gload_lds dest linear).
//      Consecutive-8 lanes now hit 8 distinct (row-parity, chunk) groups.
//  (b) gf/uf identical across mh0/mh1 phases -> load once per K-half, hold in
//      regs: 32 -> 24 ds_read_b128 per K-tile (avg 48KB/phase ~ 190cy vs
//      154cy MFMA).
// Schedule, staging order, vmcnt bookkeeping, and per-element accumulation
// order are IDENTICAL to round 3 (verified passing) — only LDS placement and
// redundant-read elimination changed.
// ---------------------------------------------------------------------------
#define FFN_RD_A(KH, MH) \
    { const short* Ap = &Ab[buf][KH][0]; \
      af[0] = *(const short8*)&Ap[(wr * 128 + ((MH) * 4 + 0) * 16 + lr) * 32 + cs8]; \
      af[1] = *(const short8*)&Ap[(wr * 128 + ((MH) * 4 + 1) * 16 + lr) * 32 + cs8]; \
      af[2] = *(const short8*)&Ap[(wr * 128 + ((MH) * 4 + 2) * 16 + lr) * 32 + cs8]; \
      af[3] = *(const short8*)&Ap[(wr * 128 + ((MH) * 4 + 3) * 16 + lr) * 32 + cs8]; }

#define FFN_RD_B(KH) \
    { const short* Bp = &Bb[buf][KH][0]; \
      gf[0] = *(const short8*)&Bp[(wc * 32 + lr) * 32 + cs8]; \
      gf[1] = *(const short8*)&Bp[(wc * 32 + 16 + lr) * 32 + cs8]; \
      uf[0] = *(const short8*)&Bp[4096 + (wc * 32 + lr) * 32 + cs8]; \
      uf[1] = *(const short8*)&Bp[4096 + (wc * 32 + 16 + lr) * 32 + cs8]; }

#define FFN_MM(MH) \
    __builtin_amdgcn_s_setprio(1); \
    { _Pragma("unroll") for (int mi = 0; mi < 4; ++mi) { \
        ag[(MH) * 4 + mi][0] = __builtin_amdgcn_mfma_f32_16x16x32_bf16(af[mi], gf[0], ag[(MH) * 4 + mi][0], 0, 0, 0); \
        ag[(MH) * 4 + mi][1] = __builtin_amdgcn_mfma_f32_16x16x32_bf16(af[mi], gf[1], ag[(MH) * 4 + mi][1], 0, 0, 0); \
        au[(MH) * 4 + mi][0] = __builtin_amdgcn_mfma_f32_16x16x32_bf16(af[mi], uf[0], au[(MH) * 4 + mi][0], 0, 0, 0); \
        au[(MH) * 4 + mi][1] = __builtin_amdgcn_mfma_f32_16x16x32_bf16(af[mi], uf[1], au[(MH) * 4 + mi][1], 0, 0, 0); } } \
    __builtin_amdgcn_s_setprio(0);

__global__ __launch_bounds__(512, 2) void gemm_ffn_kernel(
        const bf16* __restrict__ A, const bf16* __restrict__ Bg,
        const bf16* __restrict__ Bu, const float* __restrict__ biasg,
        const float* __restrict__ biasu, bf16* __restrict__ C, int K) {
    __shared__ short Ab[2][2][8192];   // [buf][khalf][256 rows x 32 cols, swz]
    __shared__ short Bb[2][2][8192];   // [buf][khalf][G 128 | U 128, swz]

    const int tid = threadIdx.x;
    const int w = tid >> 6, lane = tid & 63;
    const int wr = w >> 2, wc = w & 3;           // 2M x 4N waves
    const int lr = lane & 15, quad = lane >> 4;
    const int row0 = blockIdx.y * 256, col0 = blockIdx.x * 128;
    const int NT = K >> 6;                       // 16 K-tiles
    const int cs8 = (quad ^ ((lr >> 1) & 3)) * 8;   // swizzled read chunk

    const int sr = tid >> 2;                     // staging row 0..127
    // pre-swizzled source chunk: dest chunk (tid&3) holds global chunk
    // (tid&3) ^ ((r>>1)&3), (r>>1)&3 == (tid>>3)&3 for both 128-row halves
    const int scs = (((tid & 3) ^ ((tid >> 3) & 3))) * 8;

    auto stageA = [&](short* dst, int kcol) {
        __builtin_amdgcn_global_load_lds(
            (gas_t)(A + (size_t)(row0 + sr) * K + kcol + scs),
            (las_t)(dst + tid * 8), 16, 0, 0);
        __builtin_amdgcn_global_load_lds(
            (gas_t)(A + (size_t)(row0 + 128 + sr) * K + kcol + scs),
            (las_t)(dst + 4096 + tid * 8), 16, 0, 0);
    };
    auto stageB = [&](short* dst, int kcol) {
        __builtin_amdgcn_global_load_lds(
            (gas_t)(Bg + (size_t)(col0 + sr) * K + kcol + scs),
            (las_t)(dst + tid * 8), 16, 0, 0);
        __builtin_amdgcn_global_load_lds(
            (gas_t)(Bu + (size_t)(col0 + sr) * K + kcol + scs),
            (las_t)(dst + 4096 + tid * 8), 16, 0, 0);
    };

    floatx4 ag[8][2], au[8][2];
#pragma unroll
    for (int mi = 0; mi < 8; ++mi)
#pragma unroll
        for (int ni = 0; ni < 2; ++ni) {
            ag[mi][ni] = (floatx4){0.f, 0.f, 0.f, 0.f};
            au[mi][ni] = (floatx4){0.f, 0.f, 0.f, 0.f};
        }

    // prologue: 6 half-tiles; drain to 8 outstanding (t0A0,t0B0 landed)
    stageA(&Ab[0][0][0], 0);
    stageB(&Bb[0][0][0], 0);
    stageA(&Ab[0][1][0], 32);
    stageB(&Bb[0][1][0], 32);
    stageA(&Ab[1][0][0], 64);
    stageB(&Bb[1][0][0], 64);
    VMC(8);
    BAR;

    for (int k = 0; k < NT; ++k) {
        const int buf = k & 1;
        short8 gf[2], uf[2];
        {   // phase 1: kh0, mh0 | read af + gf/uf(kh0) | stage tile k+1 A-k1
            short8 af[4];
            FFN_RD_A(0, 0)
            FFN_RD_B(0)
            if (k + 1 < NT) stageA(&Ab[buf ^ 1][1][0], (k + 1) * 64 + 32);
            BAR; WLG;
            FFN_MM(0)
            BAR;
        }
        {   // phase 2: kh0, mh1 | af only (gf/uf in regs) | stage k+1 B-k1
            short8 af[4];
            FFN_RD_A(0, 1)
            if (k + 1 < NT) stageB(&Bb[buf ^ 1][1][0], (k + 1) * 64 + 32);
            BAR; WLG;
            FFN_MM(1)
            if (k < NT - 1) { VMC(8); } else { VMC(0); }
            BAR;
        }
        {   // phase 3: kh1, mh0 | read af + gf/uf(kh1) | stage k+2 A-k0
            short8 af[4];
            FFN_RD_A(1, 0)
            FFN_RD_B(1)
            if (k + 2 < NT) stageA(&Ab[buf][0][0], (k + 2) * 64);
            BAR; WLG;
            FFN_MM(0)
            BAR;
        }
        {   // phase 4: kh1, mh1 | af only | stage k+2 B-k0
            short8 af[4];
            FFN_RD_A(1, 1)
            if (k + 2 < NT) stageB(&Bb[buf][0][0], (k + 2) * 64);
            BAR; WLG;
            FFN_MM(1)
            if (k < NT - 2) { VMC(8); } else if (k == NT - 2) { VMC(4); }
            BAR;
        }
    }

#pragma unroll
    for (int mi = 0; mi < 8; ++mi) {
#pragma unroll
        for (int ni = 0; ni < 2; ++ni) {
            int gc = col0 + wc * 32 + ni * 16 + lr;
            float bg_ = biasg[gc], bu_ = biasu[gc];
#pragma unroll
            for (int r = 0; r < 4; ++r) {
                int gr = row0 + wr * 128 + mi * 16 + quad * 4 + r;
                float g = ag[mi][ni][r] + bg_;
                float u = au[mi][ni][r] + bu_;
                float v = 0.5f * g * (1.0f + erff(g * 0.70710678118654752f)) * u;
                C[(size_t)gr * FFF + gc] = __float2bfloat16(v);
            }
        }
    }
}

// ---------------------------------------------------------------------------
// RoPE cos/sin table: (SS x 32) each. Identical math (powf/cosf/sinf) to the
// per-element version, computed once per (s,i) instead of once per (s,i,h).
// ---------------------------------------------------------------------------
__global__ __launch_bounds__(256) void rope_table_kernel(float* __restrict__ ct,
                                                         float* __restrict__ st) {
    int idx = blockIdx.x * 256 + threadIdx.x;   // SS*32 = 65536 total
    int i = idx & 31, s = idx >> 5;
    float inv = powf(10000.0f, -(float)i / 32.0f);
    float ang = (float)s * inv;
    ct[idx] = cosf(ang);
    st[idx] = sinf(ang);
}

// ---------------------------------------------------------------------------
// RoPE on bf16 q, in place, 1/sqrt(HD) folded. pos = row % SS. Table-driven.
// ---------------------------------------------------------------------------
__global__ __launch_bounds__(256) void rope_q_kernel(bf16* __restrict__ t,
                                                     const float* __restrict__ ct,
                                                     const float* __restrict__ st,
                                                     int total) {
    int idx = blockIdx.x * 256 + threadIdx.x;
    if (idx >= total) return;
    int i = idx & 31;
    int h = (idx >> 5) % HH;
    int row = idx / (32 * HH);
    int s = row & (SS - 1);
    float c = ct[s * 32 + i];
    float sn = st[s * 32 + i];
    size_t base = (size_t)row * (HH * HD) + h * 64 + i;
    float t1 = (float)t[base];
    float t2 = (float)t[base + 32];
    t[base]      = __float2bfloat16((t1 * c - t2 * sn) * 0.125f);
    t[base + 32] = __float2bfloat16((t1 * sn + t2 * c) * 0.125f);
}

// ---------------------------------------------------------------------------
// prep_kv: kv fp32 (MROWS,128) -> kbf bf16 (MROWS,64) roped,
//          vtb bf16 (BB,64,SS) = V transposed per batch. Table-driven RoPE.
// ---------------------------------------------------------------------------
__global__ __launch_bounds__(256) void prep_kv_kernel(const float* __restrict__ kv,
                                                      const float* __restrict__ ct,
                                                      const float* __restrict__ st,
                                                      bf16* __restrict__ kbf,
                                                      bf16* __restrict__ vtb) {
    __shared__ float vt[64][65];
    int s0 = blockIdx.x * 64;
    int b  = blockIdx.y;
    int tid = threadIdx.x;

    for (int i = tid; i < 2048; i += 256) {
        int sl = i >> 5, ii = i & 31;
        int s = s0 + sl;
        size_t base = ((size_t)(b * SS + s)) * 128;
        float k1 = kv[base + ii], k2 = kv[base + ii + 32];
        float c = ct[s * 32 + ii];
        float sn = st[s * 32 + ii];
        size_t ob = ((size_t)(b * SS + s)) * 64;
        kbf[ob + ii]      = __float2bfloat16(k1 * c - k2 * sn);
        kbf[ob + ii + 32] = __float2bfloat16(k1 * sn + k2 * c);
    }

    for (int i = tid; i < 4096; i += 256) {
        int s = i >> 6, d = i & 63;
        vt[d][s] = kv[((size_t)(b * SS + s0 + s)) * 128 + 64 + d];
    }
    __syncthreads();
    for (int i = tid; i < 4096; i += 256) {
        int d = i >> 6, sl = i & 63;
        vtb[((size_t)(b * 64 + d)) * SS + s0 + sl] = __float2bfloat16(vt[d][sl]);
    }
}

// ---------------------------------------------------------------------------
// MFMA flash attention v6: fixed-shift softmax + k-split-2 (unchanged math)
// with LDS-staged, double-buffered K/V tiles. XOR-swizzled (both-sides).
// ---------------------------------------------------------------------------
#define PST 68
#define SM_SHIFT 6.0f

__global__ __launch_bounds__(256, 3) void attn_mfma_kernel(
        const bf16* __restrict__ q, const bf16* __restrict__ kb,
        const bf16* __restrict__ vt,
        float* __restrict__ O0p, float* __restrict__ O1p,
        float* __restrict__ l0p, float* __restrict__ l1p) {
    __shared__ short Kb_s[2][64 * 64];
    __shared__ short Vb_s[2][64 * 64];
    __shared__ short Ps[4][16 * PST];

    int h = blockIdx.y, b = blockIdx.z;
    int px = blockIdx.x >> 1, half = blockIdx.x & 1;
    int tid = threadIdx.x, w = tid >> 6, lane = tid & 63;
    int lr = lane & 15, quad = lane >> 4;
    int rsw = lane & 7;                 // read-side swizzle: row&7 == lr&7

    float* __restrict__ Op = half ? O1p : O0p;
    float* __restrict__ lp = half ? l1p : l0p;

    const bf16* kbB = kb + (size_t)b * SS * 64;
    const bf16* vtB = vt + (size_t)b * 64 * SS;

    int st_sub = lane >> 3;
    int st_col = ((lane & 7) ^ st_sub) << 3;      // element offset within row

    auto stage_tile = [&](int nxt, int j0s) {
#pragma unroll
        for (int i = 0; i < 2; ++i) {
            int rr = i * 32 + w * 8 + st_sub;
            __builtin_amdgcn_global_load_lds(
                (gas_t)(kbB + (size_t)(j0s + rr) * 64 + st_col),
                (las_t)&Kb_s[nxt][(i * 256 + w * 64) * 8], 16, 0, 0);
            __builtin_amdgcn_global_load_lds(
                (gas_t)(vtB + (size_t)rr * SS + j0s + st_col),
                (las_t)&Vb_s[nxt][(i * 256 + w * 64) * 8], 16, 0, 0);
        }
    };

    for (int pass = 0; pass < 2; ++pass) {
        int qt = (pass == 0) ? px : (SS / 64 - 1 - px);
        int q0 = qt * 64;

        const bf16* qrow = q + ((size_t)(b * SS + q0 + w * 16 + lr)) * (HH * HD) + h * HD;
        short8 qf0 = *(const short8*)(qrow + quad * 8);
        short8 qf1 = *(const short8*)(qrow + 32 + quad * 8);

        int n  = qt + 1;            // total k-tiles for this q-tile
        int n0 = (n + 1) >> 1;      // half 0 takes [0,n0), half 1 takes [n0,n)
        int tlo = half ? n0 : 0;
        int thi = half ? n  : n0;

        floatx4 O[4];
#pragma unroll
        for (int ni = 0; ni < 4; ++ni) O[ni] = (floatx4){0.f, 0.f, 0.f, 0.f};
        float lrow[4] = {0.f, 0.f, 0.f, 0.f};

        int cur = 0;
        if (tlo < thi) stage_tile(0, tlo * 64);
        __syncthreads();

        for (int t = tlo; t < thi; ++t) {
            // stage next tile into the other buffer (overlaps this compute)
            if (t + 1 < thi) stage_tile(cur ^ 1, (t + 1) * 64);

            int j0 = t * 64;

            // S = Q @ K^T   (K fragments from swizzled LDS)
            floatx4 S[4];
#pragma unroll
            for (int ni = 0; ni < 4; ++ni) S[ni] = (floatx4){0.f, 0.f, 0.f, 0.f};
#pragma unroll
            for (int ni = 0; ni < 4; ++ni) {
                const short* Kc = &Kb_s[cur][(ni * 16 + lr) * 64];
                short8 b0 = *(const short8*)&Kc[(quad ^ rsw) * 8];
                short8 b1 = *(const short8*)&Kc[((quad ^ rsw) ^ 4) * 8];
                S[ni] = __builtin_amdgcn_mfma_f32_16x16x32_bf16(qf0, b0, S[ni], 0, 0, 0);
                S[ni] = __builtin_amdgcn_mfma_f32_16x16x32_bf16(qf1, b1, S[ni], 0, 0, 0);
            }

            // V fragments (swizzled LDS), issued early to overlap exp + pack
            short8 vf[8];
#pragma unroll
            for (int ni = 0; ni < 4; ++ni) {
                const short* Vc = &Vb_s[cur][(ni * 16 + lr) * 64];
                vf[2 * ni]     = *(const short8*)&Vc[(quad ^ rsw) * 8];
                vf[2 * ni + 1] = *(const short8*)&Vc[((quad ^ rsw) ^ 4) * 8];
            }

            // causal mask on diagonal tile
            if (t == qt) {
                int rowg = q0 + w * 16 + quad * 4;
#pragma unroll
                for (int ni = 0; ni < 4; ++ni) {
                    int colg = j0 + ni * 16 + lr;
#pragma unroll
                    for (int r = 0; r < 4; ++r)
                        if (colg > rowg + r) S[ni][r] = -3.0e38f;
                }
            }

            // fixed-shift exp; accumulate per-lane row sums (no cross-lane ops)
#pragma unroll
            for (int ni = 0; ni < 4; ++ni)
#pragma unroll
                for (int r = 0; r < 4; ++r)
                    S[ni][r] = __expf(S[ni][r] - SM_SHIFT);
#pragma unroll
            for (int r = 0; r < 4; ++r)
                lrow[r] += S[0][r] + S[1][r] + S[2][r] + S[3][r];

            // pack P (bf16) to wave-private LDS in C-layout
#pragma unroll
            for (int ni = 0; ni < 4; ++ni)
#pragma unroll
                for (int r = 0; r < 4; ++r) {
                    bf16 pb = __float2bfloat16(S[ni][r]);
                    Ps[w][(quad * 4 + r) * PST + ni * 16 + lr] = *(short*)&pb;
                }
            short4v a0 = *(const short4v*)&Ps[w][lr * PST + quad * 8];
            short4v a1 = *(const short4v*)&Ps[w][lr * PST + quad * 8 + 4];
            short4v a2 = *(const short4v*)&Ps[w][lr * PST + 32 + quad * 8];
            short4v a3 = *(const short4v*)&Ps[w][lr * PST + 32 + quad * 8 + 4];
            short8 p0 = __builtin_shufflevector(a0, a1, 0, 1, 2, 3, 4, 5, 6, 7);
            short8 p1 = __builtin_shufflevector(a2, a3, 0, 1, 2, 3, 4, 5, 6, 7);

            // O += P @ V
#pragma unroll
            for (int ni = 0; ni < 4; ++ni) {
                O[ni] = __builtin_amdgcn_mfma_f32_16x16x32_bf16(p0, vf[2 * ni], O[ni], 0, 0, 0);
                O[ni] = __builtin_amdgcn_mfma_f32_16x16x32_bf16(p1, vf[2 * ni + 1], O[ni], 0, 0, 0);
            }

            // drains next-tile staging + ensures all waves done with cur
            __syncthreads();
            cur ^= 1;
        }

        // deferred row-sum reduction over the quad's 16 lanes (once per pass)
#pragma unroll
        for (int r = 0; r < 4; ++r) {
            float l = lrow[r];
            for (int off = 1; off < 16; off <<= 1) l += __shfl_xor(l, off, 64);
            lrow[r] = l;
        }

        // write unnormalized partials (zeros when this half's range is empty)
#pragma unroll
        for (int ni = 0; ni < 4; ++ni) {
            int gc = h * 64 + ni * 16 + lr;
#pragma unroll
            for (int r = 0; r < 4; ++r) {
                int gr = b * SS + q0 + w * 16 + quad * 4 + r;
                Op[(size_t)gr * (HH * HD) + gc] = O[ni][r];
            }
        }
        if (lr == 0) {
#pragma unroll
            for (int r = 0; r < 4; ++r) {
                int gr = b * SS + q0 + w * 16 + quad * 4 + r;
                lp[(size_t)gr * HH + h] = lrow[r];
            }
        }
    }
}

// ---------------------------------------------------------------------------
// Combine the two key-range halves: ao = (O0+O1)/(l0+l1), bf16 out.
// ---------------------------------------------------------------------------
__global__ __launch_bounds__(256) void attn_combine_kernel(
        const float* __restrict__ O0p, const float* __restrict__ O1p,
        const float* __restrict__ l0p, const float* __restrict__ l1p,
        bf16* __restrict__ o) {
    int idx = blockIdx.x * 256 + threadIdx.x;   // < MROWS*1024/4
    int d4  = idx & 15;
    int hh  = (idx >> 4) & 15;
    int row = idx >> 8;
    float l = l0p[row * HH + hh] + l1p[row * HH + hh];
    float inv = 1.0f / l;
    size_t base = (size_t)row * (HH * HD) + hh * 64 + d4 * 4;
    float4 a = *(const float4*)(O0p + base);
    float4 c = *(const float4*)(O1p + base);
    short4v o4;
    {
        bf16 v0 = __float2bfloat16((a.x + c.x) * inv);
        bf16 v1 = __float2bfloat16((a.y + c.y) * inv);
        bf16 v2 = __float2bfloat16((a.z + c.z) * inv);
        bf16 v3 = __float2bfloat16((a.w + c.w) * inv);
        o4[0] = *(short*)&v0; o4[1] = *(short*)&v1;
        o4[2] = *(short*)&v2; o4[3] = *(short*)&v3;
    }
    *(short4v*)(o + base) = o4;
}

// ---------------------------------------------------------------------------
// Launch. Workspace (byte offsets, ~87 MB):
//   qbf @0 (8 MB, dead after attn; wgT reuses @0) | wuT @8M
//   x2 @16M (fp32 16 MB, written step 6; Opart0 borrows @16M during attn)
//   h1b/h2b @32M (8 MB) | kv @40M (fp32 2 MB)
//   ao @42M (8 MB, dead after wo; wdT reuses)
//   gg @50M (32 MB; pre-FFN its body hosts kbf/vtb @50M, Opart1 @51M,
//            lparts @67M, rope tables @68M — all dead before gg is written)
//   wqkvT @82M (2.25 MB) | bqkv @84.5M | woT @85M (2 MB)
// ---------------------------------------------------------------------------
#define MB (1024ull * 1024ull)

extern "C" void kernel_launch(void* const* d_in, const int* in_sizes, int n_in,
                              void* d_out, int out_size, void* d_ws, size_t ws_size,
                              hipStream_t stream) {
    const float* x  = (const float*)d_in[0];
    const float* wq = (const float*)d_in[1];
    const float* bq = (const float*)d_in[2];
    const float* wk = (const float*)d_in[3];
    const float* bk = (const float*)d_in[4];
    const float* wv = (const float*)d_in[5];
    const float* bv = (const float*)d_in[6];
    const float* wo = (const float*)d_in[7];
    const float* bo = (const float*)d_in[8];
    const float* wg = (const float*)d_in[9];
    const float* bg = (const float*)d_in[10];
    const float* wu = (const float*)d_in[11];
    const float* bu = (const float*)d_in[12];
    const float* wd = (const float*)d_in[13];
    const float* bd = (const float*)d_in[14];
    const float* g1 = (const float*)d_in[15];
    const float* g2 = (const float*)d_in[16];
    float* out = (float*)d_out;

    char* ws = (char*)d_ws;
    bf16*  qbf   = (bf16*)(ws);
    bf16*  wuT   = (bf16*)(ws + 8 * MB);
    float* x2    = (float*)(ws + 16 * MB);
    bf16*  h1b   = (bf16*)(ws + 32 * MB);
    float* kv    = (float*)(ws + 40 * MB);
    bf16*  ao    = (bf16*)(ws + 42 * MB);
    bf16*  gg    = (bf16*)(ws + 50 * MB);
    bf16*  kbf   = (bf16*)(ws + 50 * MB);              // over gg head (dead by FFN)
    bf16*  vtb   = (bf16*)(ws + 50 * MB + 512 * 1024);
    float* Opart0 = (float*)(ws + 16 * MB);            // over x2 (written step 6)
    float* Opart1 = (float*)(ws + 51 * MB);            // inside gg body (16 MB)
    float* lpart0 = (float*)(ws + 67 * MB);            // 256 KB
    float* lpart1 = (float*)(ws + 67 * MB + 256 * 1024);
    float* ctab   = (float*)(ws + 68 * MB);            // 256 KB
    float* stab   = (float*)(ws + 68 * MB + 256 * 1024);
    bf16*  wqkvT = (bf16*)(ws + 82 * MB);              // 1152 x 1024 bf16
    float* bqkv  = (float*)(ws + 84 * MB + 512 * 1024);
    bf16*  woT   = (bf16*)(ws + 85 * MB);
    bf16*  wgT   = (bf16*)(ws);                        // over qbf (dead after attn)
    bf16*  wdT   = (bf16*)(ws + 42 * MB);              // over ao (dead after wo GEMM)
    bf16*  h2b   = h1b;

    // 1. h1 = rmsnorm(x, g1)
    rmsnorm_kernel<<<MROWS, 256, 0, stream>>>(x, g1, h1b, EE);

    // 2. weight transposes for attention block (wq|wk|wv packed rows)
    transpose_cast_kernel<<<dim3(EE / 32, EE / 32), 256, 0, stream>>>(wq, wqkvT, EE, EE);
    transpose_cast_kernel<<<dim3(HD / 32, EE / 32), 256, 0, stream>>>(wk, wqkvT + (size_t)1024 * EE, EE, HD);
    transpose_cast_kernel<<<dim3(HD / 32, EE / 32), 256, 0, stream>>>(wv, wqkvT + (size_t)1088 * EE, EE, HD);
    pack_bqkv_kernel<<<(NQKV + 255) / 256, 256, 0, stream>>>(bq, bk, bv, bqkv);
    transpose_cast_kernel<<<dim3(EE / 32, EE / 32), 256, 0, stream>>>(wo, woT, EE, EE);

    // 3. fused QKV projection
    gemm_qkv_kernel<<<dim3(NQKV / 128, MROWS / 128), 256, 0, stream>>>(
        h1b, wqkvT, bqkv, qbf, kv, EE);

    // 3.5 RoPE cos/sin table (once per launch; identical math to before)
    rope_table_kernel<<<(SS * 32) / 256, 256, 0, stream>>>(ctab, stab);

    // 4. RoPE on q (in place, 0.125 folded); kv -> kbf (roped) + vtb
    {
        int total_q = MROWS * HH * 32;
        rope_q_kernel<<<(total_q + 255) / 256, 256, 0, stream>>>(qbf, ctab, stab, total_q);
    }
    prep_kv_kernel<<<dim3(SS / 64, BB), 256, 0, stream>>>(kv, ctab, stab, kbf, vtb);

    // 5. attention partials (k-split x2) + combine -> ao [bf16]
    attn_mfma_kernel<<<dim3(2 * SS / 128, HH, BB), 256, 0, stream>>>(
        qbf, kbf, vtb, Opart0, Opart1, lpart0, lpart1);
    attn_combine_kernel<<<(MROWS * HH * HD / 4) / 256, 256, 0, stream>>>(
        Opart0, Opart1, lpart0, lpart1, ao);

    // 6. x2 = ao @ wo + bo + x  [fp32]
    gemm_n64_kernel<<<dim3(EE / 64, MROWS / 128), 256, 0, stream>>>(
        ao, woT, bo, x, x2, MROWS, EE, EE);

    // 7. h2 = rmsnorm(x2, g2)
    rmsnorm_kernel<<<MROWS, 256, 0, stream>>>(x2, g2, h2b, EE);

    // 8. FFN weight transposes (reuse dead qbf slot + wuT region)
    transpose_cast_kernel<<<dim3(FFF / 32, EE / 32), 256, 0, stream>>>(wg, wgT, EE, FFF);
    transpose_cast_kernel<<<dim3(FFF / 32, EE / 32), 256, 0, stream>>>(wu, wuT, EE, FFF);

    // 9. gg = gelu(h2@wg+bg) * (h2@wu+bu)  [fused, 8-phase + swizzle, bf16]
    gemm_ffn_kernel<<<dim3(FFF / 128, MROWS / 256), 512, 0, stream>>>(
        h2b, wgT, wuT, bg, bu, gg, EE);

    // 10. wd transpose, then out = gg @ wd + bd + x2  [fp32]
    transpose_cast_kernel<<<dim3(EE / 32, FFF / 32), 256, 0, stream>>>(wd, wdT, FFF, EE);
    gemm_n64_kernel<<<dim3(EE / 64, MROWS / 128), 256, 0, stream>>>(
        gg, wdT, bd, x2, out, MROWS, EE, FFF);
}

// Round 5
// 415.333 us; speedup vs baseline: 1.1109x; 1.0329x over previous
//
#include <hip/hip_runtime.h>
#include <hip/hip_bf16.h>
#include <math.h>

// Problem constants
#define BB 2
#define SS 2048
#define EE 1024
#define HH 16
#define HD 64
#define FFF 4096
#define MROWS (BB * SS)        // 4096
#define EPS_F 1.1920929e-7f
#define NQKV 1152              // 1024 q + 64 k + 64 v

typedef __hip_bfloat16 bf16;
typedef __attribute__((ext_vector_type(8))) short short8;
typedef __attribute__((ext_vector_type(4))) short short4v;
typedef __attribute__((ext_vector_type(4))) float floatx4;

typedef const __attribute__((address_space(1))) void* gas_t;
typedef __attribute__((address_space(3))) void* las_t;

// scheduling primitives for the 8-phase FFN kernel
#define BAR __builtin_amdgcn_s_barrier()
#define WLG do { asm volatile("s_waitcnt lgkmcnt(0)" ::: "memory"); \
                 __builtin_amdgcn_sched_barrier(0); } while (0)
#define VMC(N) asm volatile("s_waitcnt vmcnt(" #N ")" ::: "memory")

// ---------------------------------------------------------------------------
// RMSNorm: fp32 in, bf16 out
// ---------------------------------------------------------------------------
__global__ __launch_bounds__(256) void rmsnorm_kernel(const float* __restrict__ x,
                                                      const float* __restrict__ g,
                                                      bf16* __restrict__ out,
                                                      int cols) {
    int row = blockIdx.x;
    const float* xr = x + (size_t)row * cols;
    float ss = 0.0f;
    for (int c = threadIdx.x; c < cols; c += 256) {
        float v = xr[c];
        ss += v * v;
    }
    for (int off = 32; off > 0; off >>= 1) ss += __shfl_xor(ss, off, 64);
    __shared__ float red[4];
    int wave = threadIdx.x >> 6;
    if ((threadIdx.x & 63) == 0) red[wave] = ss;
    __syncthreads();
    float tot = red[0] + red[1] + red[2] + red[3];
    float rs = rsqrtf(tot / (float)cols + EPS_F);
    bf16* orow = out + (size_t)row * cols;
    for (int c = threadIdx.x; c < cols; c += 256) {
        orow[c] = __float2bfloat16(xr[c] * rs * g[c]);
    }
}

// ---------------------------------------------------------------------------
// 32x32 transpose+cast tile body (shared by the two fused weight-prep kernels)
// ---------------------------------------------------------------------------
__device__ __forceinline__ void transpose_tile32(const float* __restrict__ W,
                                                 bf16* __restrict__ Wt,
                                                 int K, int N, int bx, int by,
                                                 int tid, float (*t)[33]) {
    int n0 = bx * 32, k0 = by * 32;
    int tx = tid & 31, ty = tid >> 5;   // ty 0..7
#pragma unroll
    for (int i = 0; i < 4; ++i) {
        int kk = ty + i * 8;
        t[kk][tx] = W[(size_t)(k0 + kk) * N + n0 + tx];
    }
    __syncthreads();
#pragma unroll
    for (int i = 0; i < 4; ++i) {
        int nn = ty + i * 8;
        Wt[(size_t)(n0 + nn) * K + k0 + tx] = __float2bfloat16(t[tx][nn]);
    }
}

// ---------------------------------------------------------------------------
// Fused attention-side prep (1 launch replaces 6):
//   wq/wk/wv/wo transposes + [bq|bk|bv] pack + RoPE cos/sin tables.
// Block ranges: [0,1024) wq | [1024,1088) wk | [1088,1152) wv |
//               [1152,2176) wo | [2176,2432) rope table | [2432,2437) pack.
// ---------------------------------------------------------------------------
__global__ __launch_bounds__(256) void prep_weights_kernel(
        const float* __restrict__ wq, const float* __restrict__ wk,
        const float* __restrict__ wv, const float* __restrict__ wo,
        const float* __restrict__ bq, const float* __restrict__ bk,
        const float* __restrict__ bv,
        bf16* __restrict__ wqkvT, bf16* __restrict__ woT,
        float* __restrict__ bqkv, float* __restrict__ ct, float* __restrict__ st) {
    __shared__ float t[32][33];
    int bid = blockIdx.x, tid = threadIdx.x;
    if (bid < 1024) {
        transpose_tile32(wq, wqkvT, EE, EE, bid & 31, bid >> 5, tid, t);
    } else if (bid < 1088) {
        int b2 = bid - 1024;
        transpose_tile32(wk, wqkvT + (size_t)1024 * EE, EE, HD, b2 & 1, b2 >> 1, tid, t);
    } else if (bid < 1152) {
        int b2 = bid - 1088;
        transpose_tile32(wv, wqkvT + (size_t)1088 * EE, EE, HD, b2 & 1, b2 >> 1, tid, t);
    } else if (bid < 2176) {
        int b2 = bid - 1152;
        transpose_tile32(wo, woT, EE, EE, b2 & 31, b2 >> 5, tid, t);
    } else if (bid < 2432) {
        int idx = (bid - 2176) * 256 + tid;       // SS*32 = 65536 entries
        int i = idx & 31, s = idx >> 5;
        float inv = powf(10000.0f, -(float)i / 32.0f);
        float ang = (float)s * inv;
        ct[idx] = cosf(ang);
        st[idx] = sinf(ang);
    } else {
        int tt = (bid - 2432) * 256 + tid;
        if (tt < NQKV) {
            float v;
            if (tt < 1024)      v = bq[tt];
            else if (tt < 1088) v = bk[tt - 1024];
            else                v = bv[tt - 1088];
            bqkv[tt] = v;
        }
    }
}

// ---------------------------------------------------------------------------
// Fused FFN weight prep (1 launch replaces 3): wg/wu/wd transposes.
// [0,4096) wg | [4096,8192) wu | [8192,12288) wd.
// ---------------------------------------------------------------------------
__global__ __launch_bounds__(256) void ffn_weights_kernel(
        const float* __restrict__ wg, const float* __restrict__ wu,
        const float* __restrict__ wd,
        bf16* __restrict__ wgT, bf16* __restrict__ wuT, bf16* __restrict__ wdT) {
    __shared__ float t[32][33];
    int bid = blockIdx.x, tid = threadIdx.x;
    if (bid < 4096) {
        transpose_tile32(wg, wgT, EE, FFF, bid & 127, bid >> 7, tid, t);
    } else if (bid < 8192) {
        int b2 = bid - 4096;
        transpose_tile32(wu, wuT, EE, FFF, b2 & 127, b2 >> 7, tid, t);
    } else {
        int b2 = bid - 8192;
        transpose_tile32(wd, wdT, FFF, EE, b2 & 31, b2 >> 5, tid, t);
    }
}

// ---------------------------------------------------------------------------
// Fused QKV GEMM + RoPE epilogue: [q|k|v] = h1 @ [wq|wk|wv]^T + bqkv, then
// q-rope (x0.125 folded) and k-rope applied IN REGISTERS: the wave holding
// acc[mi][ni] also holds acc[mi][ni+2] — exactly the (i, i+32) rotation pair
// (each wn-block is one 64-aligned head span). Outputs: qbf (bf16, roped),
// kbf (bf16, roped), vb (bf16). Kills rope_q + the fp32 kv round-trip.
// k/v numerics bit-identical to the old prep_kv path; q drops one bf16
// round-trip before rotation (strictly closer to the fp32 reference).
// ---------------------------------------------------------------------------
#define GK 64

__global__ __launch_bounds__(256) void gemm_qkv_kernel(
        const bf16* __restrict__ A, const bf16* __restrict__ Bt,
        const float* __restrict__ bias,
        const float* __restrict__ ct, const float* __restrict__ st,
        bf16* __restrict__ qout, bf16* __restrict__ kout,
        bf16* __restrict__ vout, int K) {
    __shared__ short As[128 * GK];
    __shared__ short Bs[128 * GK];
    int tid = threadIdx.x;
    int wave = tid >> 6, lane = tid & 63;
    int wm = (wave >> 1) * 64, wn = (wave & 1) * 64;
    int row0 = blockIdx.y * 128, col0 = blockIdx.x * 128;
    int lr = lane & 15, lq = lane >> 4;

    int srow = wave * 32 + (lane >> 3);
    int scol = (lane & 7) * 8;
    const bf16* Abase = A + (size_t)(row0 + srow) * K + scol;
    const bf16* Bbase = Bt + (size_t)(col0 + srow) * K + scol;

    floatx4 acc[4][4];
#pragma unroll
    for (int mi = 0; mi < 4; ++mi)
#pragma unroll
        for (int ni = 0; ni < 4; ++ni)
            acc[mi][ni] = (floatx4){0.f, 0.f, 0.f, 0.f};

    for (int k0 = 0; k0 < K; k0 += GK) {
        __syncthreads();
#pragma unroll
        for (int c = 0; c < 4; ++c) {
            __builtin_amdgcn_global_load_lds(
                (gas_t)(Abase + (size_t)(c * 8) * K + k0),
                (las_t)&As[(wave * 32 + c * 8) * GK], 16, 0, 0);
            __builtin_amdgcn_global_load_lds(
                (gas_t)(Bbase + (size_t)(c * 8) * K + k0),
                (las_t)&Bs[(wave * 32 + c * 8) * GK], 16, 0, 0);
        }
        __syncthreads();
#pragma unroll
        for (int ks = 0; ks < GK; ks += 32) {
            short8 af[4], bfr[4];
#pragma unroll
            for (int mi = 0; mi < 4; ++mi)
                af[mi] = *(const short8*)&As[(wm + mi * 16 + lr) * GK + ks + lq * 8];
#pragma unroll
            for (int ni = 0; ni < 4; ++ni)
                bfr[ni] = *(const short8*)&Bs[(wn + ni * 16 + lr) * GK + ks + lq * 8];
#pragma unroll
            for (int mi = 0; mi < 4; ++mi)
#pragma unroll
                for (int ni = 0; ni < 4; ++ni)
                    acc[mi][ni] = __builtin_amdgcn_mfma_f32_16x16x32_bf16(
                        af[mi], bfr[ni], acc[mi][ni], 0, 0, 0);
        }
    }

    int hcol = col0 + wn;                 // 64-aligned head-span base
    if (hcol < 1088) {                    // q (hcol<1024) or k (hcol==1024)
        bool isQ = hcol < 1024;
#pragma unroll
        for (int mi = 0; mi < 4; ++mi) {
#pragma unroll
            for (int ni = 0; ni < 2; ++ni) {
                int i = ni * 16 + lr;
                float b1 = bias[hcol + i];
                float b2 = bias[hcol + i + 32];
#pragma unroll
                for (int r = 0; r < 4; ++r) {
                    int gr = row0 + wm + mi * 16 + lq * 4 + r;
                    int s = gr & (SS - 1);
                    float c  = ct[s * 32 + i];
                    float sn = st[s * 32 + i];
                    float t1 = acc[mi][ni][r] + b1;
                    float t2 = acc[mi][ni + 2][r] + b2;
                    float o1 = t1 * c - t2 * sn;
                    float o2 = t1 * sn + t2 * c;
                    if (isQ) {
                        qout[(size_t)gr * 1024 + hcol + i]      = __float2bfloat16(o1 * 0.125f);
                        qout[(size_t)gr * 1024 + hcol + i + 32] = __float2bfloat16(o2 * 0.125f);
                    } else {
                        kout[(size_t)gr * 64 + i]      = __float2bfloat16(o1);
                        kout[(size_t)gr * 64 + i + 32] = __float2bfloat16(o2);
                    }
                }
            }
        }
    } else {                              // v: plain bias + cast
#pragma unroll
        for (int mi = 0; mi < 4; ++mi)
#pragma unroll
            for (int ni = 0; ni < 4; ++ni) {
                int vcol = ni * 16 + lr;
                float bv_ = bias[1088 + vcol];
#pragma unroll
                for (int r = 0; r < 4; ++r) {
                    int gr = row0 + wm + mi * 16 + lq * 4 + r;
                    vout[(size_t)gr * 64 + vcol] = __float2bfloat16(acc[mi][ni][r] + bv_);
                }
            }
    }
}

// ---------------------------------------------------------------------------
// GEMM 128x64 tiles (for N=1024 outputs: wo, wd): C = A@Bt^T + bias + aux.
// 4 waves, each 32 rows x 64 cols (mi=2, ni=4). fp32 out, fp32 aux residual.
// 512 blocks = 2/CU — this parallelism is load-bearing (n128@256blocks lost).
// ---------------------------------------------------------------------------
__global__ __launch_bounds__(256) void gemm_n64_kernel(
        const bf16* __restrict__ A, const bf16* __restrict__ Bt,
        const float* __restrict__ bias, const float* __restrict__ aux,
        float* __restrict__ C, int M, int N, int K) {
    __shared__ short As[128 * GK];
    __shared__ short Bs[64 * GK];
    int tid = threadIdx.x;
    int wave = tid >> 6, lane = tid & 63;
    int wm = wave * 32;
    int row0 = blockIdx.y * 128, col0 = blockIdx.x * 64;
    int lr = lane & 15, lq = lane >> 4;

    int srow = (lane >> 3);
    int scol = (lane & 7) * 8;
    const bf16* Abase = A + (size_t)(row0 + wave * 32 + srow) * K + scol;
    const bf16* Bbase = Bt + (size_t)(col0 + wave * 16 + srow) * K + scol;

    floatx4 acc[2][4];
#pragma unroll
    for (int mi = 0; mi < 2; ++mi)
#pragma unroll
        for (int ni = 0; ni < 4; ++ni)
            acc[mi][ni] = (floatx4){0.f, 0.f, 0.f, 0.f};

    for (int k0 = 0; k0 < K; k0 += GK) {
        __syncthreads();
#pragma unroll
        for (int c = 0; c < 4; ++c)
            __builtin_amdgcn_global_load_lds(
                (gas_t)(Abase + (size_t)(c * 8) * K + k0),
                (las_t)&As[(wave * 32 + c * 8) * GK], 16, 0, 0);
#pragma unroll
        for (int c = 0; c < 2; ++c)
            __builtin_amdgcn_global_load_lds(
                (gas_t)(Bbase + (size_t)(c * 8) * K + k0),
                (las_t)&Bs[(wave * 16 + c * 8) * GK], 16, 0, 0);
        __syncthreads();
#pragma unroll
        for (int ks = 0; ks < GK; ks += 32) {
            short8 af[2], bfr[4];
#pragma unroll
            for (int mi = 0; mi < 2; ++mi)
                af[mi] = *(const short8*)&As[(wm + mi * 16 + lr) * GK + ks + lq * 8];
#pragma unroll
            for (int ni = 0; ni < 4; ++ni)
                bfr[ni] = *(const short8*)&Bs[(ni * 16 + lr) * GK + ks + lq * 8];
#pragma unroll
            for (int mi = 0; mi < 2; ++mi)
#pragma unroll
                for (int ni = 0; ni < 4; ++ni)
                    acc[mi][ni] = __builtin_amdgcn_mfma_f32_16x16x32_bf16(
                        af[mi], bfr[ni], acc[mi][ni], 0, 0, 0);
        }
    }

#pragma unroll
    for (int mi = 0; mi < 2; ++mi) {
#pragma unroll
        for (int ni = 0; ni < 4; ++ni) {
            int gc = col0 + ni * 16 + lr;
            float bv = bias[gc];
#pragma unroll
            for (int r = 0; r < 4; ++r) {
                int gr = row0 + wm + mi * 16 + lq * 4 + r;
                size_t idx = (size_t)gr * N + gc;
                C[idx] = acc[mi][ni][r] + bv + aux[idx];
            }
        }
    }
}

// ---------------------------------------------------------------------------
// Fused FFN GEMM, 8-phase schedule (T2+T3+T4+T5), swizzled + B-reg-reuse.
// Unchanged from round 4 (89.7us, 0 bank conflicts, passing).
// ---------------------------------------------------------------------------
#define FFN_RD_A(KH, MH) \
    { const short* Ap = &Ab[buf][KH][0]; \
      af[0] = *(const short8*)&Ap[(wr * 128 + ((MH) * 4 + 0) * 16 + lr) * 32 + cs8]; \
      af[1] = *(const short8*)&Ap[(wr * 128 + ((MH) * 4 + 1) * 16 + lr) * 32 + cs8]; \
      af[2] = *(const short8*)&Ap[(wr * 128 + ((MH) * 4 + 2) * 16 + lr) * 32 + cs8]; \
      af[3] = *(const short8*)&Ap[(wr * 128 + ((MH) * 4 + 3) * 16 + lr) * 32 + cs8]; }

#define FFN_RD_B(KH) \
    { const short* Bp = &Bb[buf][KH][0]; \
      gf[0] = *(const short8*)&Bp[(wc * 32 + lr) * 32 + cs8]; \
      gf[1] = *(const short8*)&Bp[(wc * 32 + 16 + lr) * 32 + cs8]; \
      uf[0] = *(const short8*)&Bp[4096 + (wc * 32 + lr) * 32 + cs8]; \
      uf[1] = *(const short8*)&Bp[4096 + (wc * 32 + 16 + lr) * 32 + cs8]; }

#define FFN_MM(MH) \
    __builtin_amdgcn_s_setprio(1); \
    { _Pragma("unroll") for (int mi = 0; mi < 4; ++mi) { \
        ag[(MH) * 4 + mi][0] = __builtin_amdgcn_mfma_f32_16x16x32_bf16(af[mi], gf[0], ag[(MH) * 4 + mi][0], 0, 0, 0); \
        ag[(MH) * 4 + mi][1] = __builtin_amdgcn_mfma_f32_16x16x32_bf16(af[mi], gf[1], ag[(MH) * 4 + mi][1], 0, 0, 0); \
        au[(MH) * 4 + mi][0] = __builtin_amdgcn_mfma_f32_16x16x32_bf16(af[mi], uf[0], au[(MH) * 4 + mi][0], 0, 0, 0); \
        au[(MH) * 4 + mi][1] = __builtin_amdgcn_mfma_f32_16x16x32_bf16(af[mi], uf[1], au[(MH) * 4 + mi][1], 0, 0, 0); } } \
    __builtin_amdgcn_s_setprio(0);

__global__ __launch_bounds__(512, 2) void gemm_ffn_kernel(
        const bf16* __restrict__ A, const bf16* __restrict__ Bg,
        const bf16* __restrict__ Bu, const float* __restrict__ biasg,
        const float* __restrict__ biasu, bf16* __restrict__ C, int K) {
    __shared__ short Ab[2][2][8192];   // [buf][khalf][256 rows x 32 cols, swz]
    __shared__ short Bb[2][2][8192];   // [buf][khalf][G 128 | U 128, swz]

    const int tid = threadIdx.x;
    const int w = tid >> 6, lane = tid & 63;
    const int wr = w >> 2, wc = w & 3;           // 2M x 4N waves
    const int lr = lane & 15, quad = lane >> 4;
    const int row0 = blockIdx.y * 256, col0 = blockIdx.x * 128;
    const int NT = K >> 6;                       // 16 K-tiles
    const int cs8 = (quad ^ ((lr >> 1) & 3)) * 8;   // swizzled read chunk

    const int sr = tid >> 2;                     // staging row 0..127
    const int scs = (((tid & 3) ^ ((tid >> 3) & 3))) * 8;

    auto stageA = [&](short* dst, int kcol) {
        __builtin_amdgcn_global_load_lds(
            (gas_t)(A + (size_t)(row0 + sr) * K + kcol + scs),
            (las_t)(dst + tid * 8), 16, 0, 0);
        __builtin_amdgcn_global_load_lds(
            (gas_t)(A + (size_t)(row0 + 128 + sr) * K + kcol + scs),
            (las_t)(dst + 4096 + tid * 8), 16, 0, 0);
    };
    auto stageB = [&](short* dst, int kcol) {
        __builtin_amdgcn_global_load_lds(
            (gas_t)(Bg + (size_t)(col0 + sr) * K + kcol + scs),
            (las_t)(dst + tid * 8), 16, 0, 0);
        __builtin_amdgcn_global_load_lds(
            (gas_t)(Bu + (size_t)(col0 + sr) * K + kcol + scs),
            (las_t)(dst + 4096 + tid * 8), 16, 0, 0);
    };

    floatx4 ag[8][2], au[8][2];
#pragma unroll
    for (int mi = 0; mi < 8; ++mi)
#pragma unroll
        for (int ni = 0; ni < 2; ++ni) {
            ag[mi][ni] = (floatx4){0.f, 0.f, 0.f, 0.f};
            au[mi][ni] = (floatx4){0.f, 0.f, 0.f, 0.f};
        }

    // prologue: 6 half-tiles; drain to 8 outstanding (t0A0,t0B0 landed)
    stageA(&Ab[0][0][0], 0);
    stageB(&Bb[0][0][0], 0);
    stageA(&Ab[0][1][0], 32);
    stageB(&Bb[0][1][0], 32);
    stageA(&Ab[1][0][0], 64);
    stageB(&Bb[1][0][0], 64);
    VMC(8);
    BAR;

    for (int k = 0; k < NT; ++k) {
        const int buf = k & 1;
        short8 gf[2], uf[2];
        {   // phase 1: kh0, mh0 | read af + gf/uf(kh0) | stage tile k+1 A-k1
            short8 af[4];
            FFN_RD_A(0, 0)
            FFN_RD_B(0)
            if (k + 1 < NT) stageA(&Ab[buf ^ 1][1][0], (k + 1) * 64 + 32);
            BAR; WLG;
            FFN_MM(0)
            BAR;
        }
        {   // phase 2: kh0, mh1 | af only (gf/uf in regs) | stage k+1 B-k1
            short8 af[4];
            FFN_RD_A(0, 1)
            if (k + 1 < NT) stageB(&Bb[buf ^ 1][1][0], (k + 1) * 64 + 32);
            BAR; WLG;
            FFN_MM(1)
            if (k < NT - 1) { VMC(8); } else { VMC(0); }
            BAR;
        }
        {   // phase 3: kh1, mh0 | read af + gf/uf(kh1) | stage k+2 A-k0
            short8 af[4];
            FFN_RD_A(1, 0)
            FFN_RD_B(1)
            if (k + 2 < NT) stageA(&Ab[buf][0][0], (k + 2) * 64);
            BAR; WLG;
            FFN_MM(0)
            BAR;
        }
        {   // phase 4: kh1, mh1 | af only | stage k+2 B-k0
            short8 af[4];
            FFN_RD_A(1, 1)
            if (k + 2 < NT) stageB(&Bb[buf][0][0], (k + 2) * 64);
            BAR; WLG;
            FFN_MM(1)
            if (k < NT - 2) { VMC(8); } else if (k == NT - 2) { VMC(4); }
            BAR;
        }
    }

#pragma unroll
    for (int mi = 0; mi < 8; ++mi) {
#pragma unroll
        for (int ni = 0; ni < 2; ++ni) {
            int gc = col0 + wc * 32 + ni * 16 + lr;
            float bg_ = biasg[gc], bu_ = biasu[gc];
#pragma unroll
            for (int r = 0; r < 4; ++r) {
                int gr = row0 + wr * 128 + mi * 16 + quad * 4 + r;
                float g = ag[mi][ni][r] + bg_;
                float u = au[mi][ni][r] + bu_;
                float v = 0.5f * g * (1.0f + erff(g * 0.70710678118654752f)) * u;
                C[(size_t)gr * FFF + gc] = __float2bfloat16(v);
            }
        }
    }
}

// ---------------------------------------------------------------------------
// prep_v: vb bf16 (MROWS,64) -> vtb bf16 (BB,64,SS) transposed per batch.
// (RoPE for q/k now lives in the QKV epilogue; this is a pure transpose.)
// ---------------------------------------------------------------------------
__global__ __launch_bounds__(256) void prep_v_kernel(const bf16* __restrict__ vb,
                                                     bf16* __restrict__ vtb) {
    __shared__ short t[64][65];
    int s0 = blockIdx.x * 64, b = blockIdx.y;
    int tid = threadIdx.x;
    const short* vs = (const short*)vb;
    short* vd = (short*)vtb;
    for (int i = tid; i < 4096; i += 256) {
        int s = i >> 6, d = i & 63;
        t[d][s] = vs[((size_t)(b * SS + s0 + s)) * 64 + d];
    }
    __syncthreads();
    for (int i = tid; i < 4096; i += 256) {
        int d = i >> 6, sl = i & 63;
        vd[((size_t)(b * 64 + d)) * SS + s0 + sl] = t[d][sl];
    }
}

// ---------------------------------------------------------------------------
// MFMA flash attention v6: fixed-shift softmax + k-split-2 (unchanged math)
// with LDS-staged, double-buffered K/V tiles. XOR-swizzled (both-sides).
// ---------------------------------------------------------------------------
#define PST 68
#define SM_SHIFT 6.0f

__global__ __launch_bounds__(256, 3) void attn_mfma_kernel(
        const bf16* __restrict__ q, const bf16* __restrict__ kb,
        const bf16* __restrict__ vt,
        float* __restrict__ O0p, float* __restrict__ O1p,
        float* __restrict__ l0p, float* __restrict__ l1p) {
    __shared__ short Kb_s[2][64 * 64];
    __shared__ short Vb_s[2][64 * 64];
    __shared__ short Ps[4][16 * PST];

    int h = blockIdx.y, b = blockIdx.z;
    int px = blockIdx.x >> 1, half = blockIdx.x & 1;
    int tid = threadIdx.x, w = tid >> 6, lane = tid & 63;
    int lr = lane & 15, quad = lane >> 4;
    int rsw = lane & 7;                 // read-side swizzle: row&7 == lr&7

    float* __restrict__ Op = half ? O1p : O0p;
    float* __restrict__ lp = half ? l1p : l0p;

    const bf16* kbB = kb + (size_t)b * SS * 64;
    const bf16* vtB = vt + (size_t)b * 64 * SS;

    int st_sub = lane >> 3;
    int st_col = ((lane & 7) ^ st_sub) << 3;      // element offset within row

    auto stage_tile = [&](int nxt, int j0s) {
#pragma unroll
        for (int i = 0; i < 2; ++i) {
            int rr = i * 32 + w * 8 + st_sub;
            __builtin_amdgcn_global_load_lds(
                (gas_t)(kbB + (size_t)(j0s + rr) * 64 + st_col),
                (las_t)&Kb_s[nxt][(i * 256 + w * 64) * 8], 16, 0, 0);
            __builtin_amdgcn_global_load_lds(
                (gas_t)(vtB + (size_t)rr * SS + j0s + st_col),
                (las_t)&Vb_s[nxt][(i * 256 + w * 64) * 8], 16, 0, 0);
        }
    };

    for (int pass = 0; pass < 2; ++pass) {
        int qt = (pass == 0) ? px : (SS / 64 - 1 - px);
        int q0 = qt * 64;

        const bf16* qrow = q + ((size_t)(b * SS + q0 + w * 16 + lr)) * (HH * HD) + h * HD;
        short8 qf0 = *(const short8*)(qrow + quad * 8);
        short8 qf1 = *(const short8*)(qrow + 32 + quad * 8);

        int n  = qt + 1;            // total k-tiles for this q-tile
        int n0 = (n + 1) >> 1;      // half 0 takes [0,n0), half 1 takes [n0,n)
        int tlo = half ? n0 : 0;
        int thi = half ? n  : n0;

        floatx4 O[4];
#pragma unroll
        for (int ni = 0; ni < 4; ++ni) O[ni] = (floatx4){0.f, 0.f, 0.f, 0.f};
        float lrow[4] = {0.f, 0.f, 0.f, 0.f};

        int cur = 0;
        if (tlo < thi) stage_tile(0, tlo * 64);
        __syncthreads();

        for (int t = tlo; t < thi; ++t) {
            // stage next tile into the other buffer (overlaps this compute)
            if (t + 1 < thi) stage_tile(cur ^ 1, (t + 1) * 64);

            int j0 = t * 64;

            // S = Q @ K^T   (K fragments from swizzled LDS)
            floatx4 S[4];
#pragma unroll
            for (int ni = 0; ni < 4; ++ni) S[ni] = (floatx4){0.f, 0.f, 0.f, 0.f};
#pragma unroll
            for (int ni = 0; ni < 4; ++ni) {
                const short* Kc = &Kb_s[cur][(ni * 16 + lr) * 64];
                short8 b0 = *(const short8*)&Kc[(quad ^ rsw) * 8];
                short8 b1 = *(const short8*)&Kc[((quad ^ rsw) ^ 4) * 8];
                S[ni] = __builtin_amdgcn_mfma_f32_16x16x32_bf16(qf0, b0, S[ni], 0, 0, 0);
                S[ni] = __builtin_amdgcn_mfma_f32_16x16x32_bf16(qf1, b1, S[ni], 0, 0, 0);
            }

            // V fragments (swizzled LDS), issued early to overlap exp + pack
            short8 vf[8];
#pragma unroll
            for (int ni = 0; ni < 4; ++ni) {
                const short* Vc = &Vb_s[cur][(ni * 16 + lr) * 64];
                vf[2 * ni]     = *(const short8*)&Vc[(quad ^ rsw) * 8];
                vf[2 * ni + 1] = *(const short8*)&Vc[((quad ^ rsw) ^ 4) * 8];
            }

            // causal mask on diagonal tile
            if (t == qt) {
                int rowg = q0 + w * 16 + quad * 4;
#pragma unroll
                for (int ni = 0; ni < 4; ++ni) {
                    int colg = j0 + ni * 16 + lr;
#pragma unroll
                    for (int r = 0; r < 4; ++r)
                        if (colg > rowg + r) S[ni][r] = -3.0e38f;
                }
            }

            // fixed-shift exp; accumulate per-lane row sums (no cross-lane ops)
#pragma unroll
            for (int ni = 0; ni < 4; ++ni)
#pragma unroll
                for (int r = 0; r < 4; ++r)
                    S[ni][r] = __expf(S[ni][r] - SM_SHIFT);
#pragma unroll
            for (int r = 0; r < 4; ++r)
                lrow[r] += S[0][r] + S[1][r] + S[2][r] + S[3][r];

            // pack P (bf16) to wave-private LDS in C-layout
#pragma unroll
            for (int ni = 0; ni < 4; ++ni)
#pragma unroll
                for (int r = 0; r < 4; ++r) {
                    bf16 pb = __float2bfloat16(S[ni][r]);
                    Ps[w][(quad * 4 + r) * PST + ni * 16 + lr] = *(short*)&pb;
                }
            short4v a0 = *(const short4v*)&Ps[w][lr * PST + quad * 8];
            short4v a1 = *(const short4v*)&Ps[w][lr * PST + quad * 8 + 4];
            short4v a2 = *(const short4v*)&Ps[w][lr * PST + 32 + quad * 8];
            short4v a3 = *(const short4v*)&Ps[w][lr * PST + 32 + quad * 8 + 4];
            short8 p0 = __builtin_shufflevector(a0, a1, 0, 1, 2, 3, 4, 5, 6, 7);
            short8 p1 = __builtin_shufflevector(a2, a3, 0, 1, 2, 3, 4, 5, 6, 7);

            // O += P @ V
#pragma unroll
            for (int ni = 0; ni < 4; ++ni) {
                O[ni] = __builtin_amdgcn_mfma_f32_16x16x32_bf16(p0, vf[2 * ni], O[ni], 0, 0, 0);
                O[ni] = __builtin_amdgcn_mfma_f32_16x16x32_bf16(p1, vf[2 * ni + 1], O[ni], 0, 0, 0);
            }

            // drains next-tile staging + ensures all waves done with cur
            __syncthreads();
            cur ^= 1;
        }

        // deferred row-sum reduction over the quad's 16 lanes (once per pass)
#pragma unroll
        for (int r = 0; r < 4; ++r) {
            float l = lrow[r];
            for (int off = 1; off < 16; off <<= 1) l += __shfl_xor(l, off, 64);
            lrow[r] = l;
        }

        // write unnormalized partials (zeros when this half's range is empty)
#pragma unroll
        for (int ni = 0; ni < 4; ++ni) {
            int gc = h * 64 + ni * 16 + lr;
#pragma unroll
            for (int r = 0; r < 4; ++r) {
                int gr = b * SS + q0 + w * 16 + quad * 4 + r;
                Op[(size_t)gr * (HH * HD) + gc] = O[ni][r];
            }
        }
        if (lr == 0) {
#pragma unroll
            for (int r = 0; r < 4; ++r) {
                int gr = b * SS + q0 + w * 16 + quad * 4 + r;
                lp[(size_t)gr * HH + h] = lrow[r];
            }
        }
    }
}

// ---------------------------------------------------------------------------
// Combine the two key-range halves: ao = (O0+O1)/(l0+l1), bf16 out.
// ---------------------------------------------------------------------------
__global__ __launch_bounds__(256) void attn_combine_kernel(
        const float* __restrict__ O0p, const float* __restrict__ O1p,
        const float* __restrict__ l0p, const float* __restrict__ l1p,
        bf16* __restrict__ o) {
    int idx = blockIdx.x * 256 + threadIdx.x;   // < MROWS*1024/4
    int d4  = idx & 15;
    int hh  = (idx >> 4) & 15;
    int row = idx >> 8;
    float l = l0p[row * HH + hh] + l1p[row * HH + hh];
    float inv = 1.0f / l;
    size_t base = (size_t)row * (HH * HD) + hh * 64 + d4 * 4;
    float4 a = *(const float4*)(O0p + base);
    float4 c = *(const float4*)(O1p + base);
    short4v o4;
    {
        bf16 v0 = __float2bfloat16((a.x + c.x) * inv);
        bf16 v1 = __float2bfloat16((a.y + c.y) * inv);
        bf16 v2 = __float2bfloat16((a.z + c.z) * inv);
        bf16 v3 = __float2bfloat16((a.w + c.w) * inv);
        o4[0] = *(short*)&v0; o4[1] = *(short*)&v1;
        o4[2] = *(short*)&v2; o4[3] = *(short*)&v3;
    }
    *(short4v*)(o + base) = o4;
}

// ---------------------------------------------------------------------------
// Launch (11 dispatches; was 19). Workspace (byte offsets, ~87 MB):
//   qbf @0 (8 MB, dead after attn; wgT reuses @0) | wuT @8M
//   x2 @16M (fp32 16 MB, written at wo; Opart0 borrows @16M during attn)
//   h1b/h2b @32M (8 MB) | vb @40M (bf16 0.5 MB, old kv slot)
//   ao @42M (8 MB, dead after wo; wdT reuses)
//   gg @50M (32 MB; pre-FFN its body hosts kbf @50M, vtb @50.5M, Opart1 @51M,
//            lparts @67M, rope tables @68M — all dead before gg is written)
//   wqkvT @82M (2.25 MB) | bqkv @84.5M | woT @85M (2 MB)
// ---------------------------------------------------------------------------
#define MB (1024ull * 1024ull)

extern "C" void kernel_launch(void* const* d_in, const int* in_sizes, int n_in,
                              void* d_out, int out_size, void* d_ws, size_t ws_size,
                              hipStream_t stream) {
    const float* x  = (const float*)d_in[0];
    const float* wq = (const float*)d_in[1];
    const float* bq = (const float*)d_in[2];
    const float* wk = (const float*)d_in[3];
    const float* bk = (const float*)d_in[4];
    const float* wv = (const float*)d_in[5];
    const float* bv = (const float*)d_in[6];
    const float* wo = (const float*)d_in[7];
    const float* bo = (const float*)d_in[8];
    const float* wg = (const float*)d_in[9];
    const float* bg = (const float*)d_in[10];
    const float* wu = (const float*)d_in[11];
    const float* bu = (const float*)d_in[12];
    const float* wd = (const float*)d_in[13];
    const float* bd = (const float*)d_in[14];
    const float* g1 = (const float*)d_in[15];
    const float* g2 = (const float*)d_in[16];
    float* out = (float*)d_out;

    char* ws = (char*)d_ws;
    bf16*  qbf   = (bf16*)(ws);
    bf16*  wuT   = (bf16*)(ws + 8 * MB);
    float* x2    = (float*)(ws + 16 * MB);
    bf16*  h1b   = (bf16*)(ws + 32 * MB);
    bf16*  vb    = (bf16*)(ws + 40 * MB);
    bf16*  ao    = (bf16*)(ws + 42 * MB);
    bf16*  gg    = (bf16*)(ws + 50 * MB);
    bf16*  kbf   = (bf16*)(ws + 50 * MB);              // over gg head (dead by FFN)
    bf16*  vtb   = (bf16*)(ws + 50 * MB + 512 * 1024);
    float* Opart0 = (float*)(ws + 16 * MB);            // over x2 (written at wo)
    float* Opart1 = (float*)(ws + 51 * MB);            // inside gg body (16 MB)
    float* lpart0 = (float*)(ws + 67 * MB);            // 256 KB
    float* lpart1 = (float*)(ws + 67 * MB + 256 * 1024);
    float* ctab   = (float*)(ws + 68 * MB);            // 256 KB
    float* stab   = (float*)(ws + 68 * MB + 256 * 1024);
    bf16*  wqkvT = (bf16*)(ws + 82 * MB);              // 1152 x 1024 bf16
    float* bqkv  = (float*)(ws + 84 * MB + 512 * 1024);
    bf16*  woT   = (bf16*)(ws + 85 * MB);
    bf16*  wgT   = (bf16*)(ws);                        // over qbf (dead after attn)
    bf16*  wdT   = (bf16*)(ws + 42 * MB);              // over ao (dead after wo GEMM)
    bf16*  h2b   = h1b;

    // 1. fused attention-side weight prep (transposes + bias pack + tables)
    prep_weights_kernel<<<2437, 256, 0, stream>>>(
        wq, wk, wv, wo, bq, bk, bv, wqkvT, woT, bqkv, ctab, stab);

    // 2. h1 = rmsnorm(x, g1)
    rmsnorm_kernel<<<MROWS, 256, 0, stream>>>(x, g1, h1b, EE);

    // 3. fused QKV projection + RoPE epilogue -> qbf, kbf, vb
    gemm_qkv_kernel<<<dim3(NQKV / 128, MROWS / 128), 256, 0, stream>>>(
        h1b, wqkvT, bqkv, ctab, stab, qbf, kbf, vb, EE);

    // 4. v transpose -> vtb
    prep_v_kernel<<<dim3(SS / 64, BB), 256, 0, stream>>>(vb, vtb);

    // 5. attention partials (k-split x2) + combine -> ao [bf16]
    attn_mfma_kernel<<<dim3(2 * SS / 128, HH, BB), 256, 0, stream>>>(
        qbf, kbf, vtb, Opart0, Opart1, lpart0, lpart1);
    attn_combine_kernel<<<(MROWS * HH * HD / 4) / 256, 256, 0, stream>>>(
        Opart0, Opart1, lpart0, lpart1, ao);

    // 6. x2 = ao @ wo + bo + x  [fp32]
    gemm_n64_kernel<<<dim3(EE / 64, MROWS / 128), 256, 0, stream>>>(
        ao, woT, bo, x, x2, MROWS, EE, EE);

    // 7. h2 = rmsnorm(x2, g2)
    rmsnorm_kernel<<<MROWS, 256, 0, stream>>>(x2, g2, h2b, EE);

    // 8. fused FFN weight prep (wg/wu/wd transposes; qbf+ao now dead)
    ffn_weights_kernel<<<12288, 256, 0, stream>>>(wg, wu, wd, wgT, wuT, wdT);

    // 9. gg = gelu(h2@wg+bg) * (h2@wu+bu)  [fused, 8-phase + swizzle, bf16]
    gemm_ffn_kernel<<<dim3(FFF / 128, MROWS / 256), 512, 0, stream>>>(
        h2b, wgT, wuT, bg, bu, gg, EE);

    // 10. out = gg @ wd + bd + x2  [fp32]
    gemm_n64_kernel<<<dim3(EE / 64, MROWS / 128), 256, 0, stream>>>(
        gg, wdT, bd, x2, out, MROWS, EE, FFF);
}